// Round 1
// baseline (1984.293 us; speedup 1.0000x reference)
//
#include <hip/hip_runtime.h>
#include <cstdint>
#include <vector>
#include <algorithm>
#include <numeric>
#include <cstring>

#define NROIS  4000
#define NCH    128
#define NBINS  49
#define N_POSA 1000
#define N_NEGA 200000
#define POOLN  20000
#define SORTN  32768
#define LCHUNK 4096

// ---------------------------------------------------------------------------
// ROI align: one block per ROI. Phase 1: 49 bin geometries into LDS.
// Phase 2: 128*49 outputs, coalesced writes, 4 gathers each.
// ---------------------------------------------------------------------------
__global__ __launch_bounds__(256) void k_roi(
    const float* __restrict__ f0, const float* __restrict__ f1,
    const float* __restrict__ f2, const float* __restrict__ f3,
    const float* __restrict__ rois, float* __restrict__ out)
{
    __shared__ int   s_a[NBINS][4];
    __shared__ float s_w[NBINS][4];
    const int n   = blockIdx.x;
    const int tid = threadIdx.x;

    const float ry1 = rois[n*5+0], rx1 = rois[n*5+1];
    const float ry2 = rois[n*5+2], rx2 = rois[n*5+3];
    const int   b   = (int)rois[n*5+4];
    const float h = ry2 - ry1, w = rx2 - rx1;
    // jnp.round == round-half-even == rintf
    const float lraw = rintf(4.0f + log2f(sqrtf(h*w + 1e-12f)));
    int lvl = (int)lraw; lvl = lvl < 0 ? 0 : (lvl > 3 ? 3 : lvl);
    const int H = 256 >> lvl;
    const float* f = (lvl==0) ? f0 : (lvl==1) ? f1 : (lvl==2) ? f2 : f3;

    const float Hf  = (float)H;
    const float y1p = ry1*Hf, x1p = rx1*Hf, y2p = ry2*Hf, x2p = rx2*Hf;
    const float bh = (y2p - y1p) / 7.0f, bw = (x2p - x1p) / 7.0f;

    if (tid < NBINS) {
        const int py = tid / 7, px = tid % 7;
        float sy = y1p + bh*((float)py + 0.5f);
        float sx = x1p + bw*((float)px + 0.5f);
        sy = fminf(fmaxf(sy, 0.0f), Hf - 1.0f);
        sx = fminf(fmaxf(sx, 0.0f), Hf - 1.0f);
        const float y0f = floorf(sy), x0f = floorf(sx);
        const int y0 = (int)y0f, x0 = (int)x0f;
        const int y1i = min(y0+1, H-1), x1i = min(x0+1, H-1);
        const float wy = sy - y0f, wx = sx - x0f;
        s_a[tid][0] = y0 *H + x0;
        s_a[tid][1] = y0 *H + x1i;
        s_a[tid][2] = y1i*H + x0;
        s_a[tid][3] = y1i*H + x1i;
        const float omy = 1.0f - wy, omx = 1.0f - wx;
        s_w[tid][0] = omy*omx; s_w[tid][1] = omy*wx;
        s_w[tid][2] = wy *omx; s_w[tid][3] = wy *wx;
    }
    __syncthreads();

    const int hw = H*H;
    const float* basep = f + (size_t)b * NCH * hw;
    float* outn = out + (size_t)n * (NCH*NBINS);
    for (int t = tid; t < NCH*NBINS; t += 256) {
        const int c   = t / NBINS;
        const int bin = t - c*NBINS;
        const float* p = basep + (size_t)c * hw;
        float v = p[s_a[bin][0]]*s_w[bin][0] + p[s_a[bin][1]]*s_w[bin][1]
                + p[s_a[bin][2]]*s_w[bin][2] + p[s_a[bin][3]]*s_w[bin][3];
        outn[t] = v;
    }
}

// ---------------------------------------------------------------------------
// OHEM: select 20000 smallest d = l0-l1 (== smallest bg prob) in stable order.
// monotone float->uint mapping; 65536-bin histogram select; bitonic sort of
// 64-bit keys (bits<<32 | index).
// ---------------------------------------------------------------------------
__device__ __forceinline__ unsigned int monobits(float x) {
    unsigned int u = __float_as_uint(x);
    return (u & 0x80000000u) ? ~u : (u | 0x80000000u);
}

__global__ void k_hist(const float* __restrict__ logits, unsigned int* __restrict__ hist)
{
    const int i = blockIdx.x*256 + threadIdx.x;
    if (i >= N_NEGA) return;
    const float l0 = logits[(size_t)(N_POSA+i)*2+0];
    const float l1 = logits[(size_t)(N_POSA+i)*2+1];
    atomicAdd(&hist[monobits(l0 - l1) >> 16], 1u);
}

__global__ __launch_bounds__(1024) void k_scan(const unsigned int* __restrict__ hist,
                                               unsigned int* __restrict__ sel)
{
    __shared__ unsigned int part[1024];
    const int t = threadIdx.x;
    unsigned int s = 0;
    for (int k = 0; k < 64; ++k) s += hist[t*64+k];
    part[t] = s;
    __syncthreads();
    for (int off = 1; off < 1024; off <<= 1) {
        unsigned int v = (t >= off) ? part[t-off] : 0u;
        __syncthreads();
        part[t] += v;
        __syncthreads();
    }
    const unsigned int prev = (t == 0) ? 0u : part[t-1];
    if (prev < POOLN && part[t] >= POOLN) {
        unsigned int run = prev;
        int B = t*64;
        for (int k = 0; k < 64; ++k) {
            run += hist[t*64+k];
            if (run >= POOLN) { B = t*64+k; break; }
        }
        sel[0] = (unsigned int)B;
    }
    if (t == 0) sel[1] = 0u;
}

__global__ void k_initkeys(unsigned long long* __restrict__ key)
{
    const int i = blockIdx.x*256 + threadIdx.x;
    if (i < SORTN) key[i] = ~0ull;
}

__global__ void k_fill(const float* __restrict__ logits, unsigned int* __restrict__ sel,
                       unsigned long long* __restrict__ key)
{
    const int i = blockIdx.x*256 + threadIdx.x;
    if (i >= N_NEGA) return;
    const float l0 = logits[(size_t)(N_POSA+i)*2+0];
    const float l1 = logits[(size_t)(N_POSA+i)*2+1];
    const unsigned int bits = monobits(l0 - l1);
    if ((bits >> 16) <= sel[0]) {
        unsigned int pos = atomicAdd(&sel[1], 1u);
        if (pos < SORTN) key[pos] = ((unsigned long long)bits << 32) | (unsigned int)i;
    }
}

// -------- bitonic sort of SORTN 64-bit keys (unique keys -> stable order) ---
__global__ __launch_bounds__(1024) void k_sort_local(unsigned long long* __restrict__ key)
{
    __shared__ unsigned long long s[LCHUNK];
    const int t = threadIdx.x;
    const int base = blockIdx.x * LCHUNK;
    for (int k = t; k < LCHUNK; k += 1024) s[k] = key[base+k];
    __syncthreads();
    for (int ksz = 2; ksz <= LCHUNK; ksz <<= 1) {
        for (int j = ksz>>1; j >= 1; j >>= 1) {
            for (int p = t; p < LCHUNK/2; p += 1024) {
                const int i = ((p & ~(j-1)) << 1) | (p & (j-1));
                const int l = i | j;
                const bool up = (((base + i) & ksz) == 0);
                unsigned long long a = s[i], b = s[l];
                if ((a > b) == up) { s[i] = b; s[l] = a; }
            }
            __syncthreads();
        }
    }
    for (int k = t; k < LCHUNK; k += 1024) key[base+k] = s[k];
}

__global__ void k_sort_global(unsigned long long* __restrict__ key, int ksz, int j)
{
    const int p = blockIdx.x*256 + threadIdx.x;
    if (p >= SORTN/2) return;
    const int i = ((p & ~(j-1)) << 1) | (p & (j-1));
    const int l = i | j;
    const bool up = ((i & ksz) == 0);
    unsigned long long a = key[i], b = key[l];
    if ((a > b) == up) { key[i] = b; key[l] = a; }
}

__global__ __launch_bounds__(1024) void k_sort_merge(unsigned long long* __restrict__ key, int ksz)
{
    __shared__ unsigned long long s[LCHUNK];
    const int t = threadIdx.x;
    const int base = blockIdx.x * LCHUNK;
    for (int k = t; k < LCHUNK; k += 1024) s[k] = key[base+k];
    __syncthreads();
    for (int j = LCHUNK/2; j >= 1; j >>= 1) {
        for (int p = t; p < LCHUNK/2; p += 1024) {
            const int i = ((p & ~(j-1)) << 1) | (p & (j-1));
            const int l = i | j;
            const bool up = (((base + i) & ksz) == 0);
            unsigned long long a = s[i], b = s[l];
            if ((a > b) == up) { s[i] = b; s[l] = a; }
        }
        __syncthreads();
    }
    for (int k = t; k < LCHUNK; k += 1024) key[base+k] = s[k];
}

// ---------------------------------------------------------------------------
// losses
// ---------------------------------------------------------------------------
__global__ __launch_bounds__(256) void k_pos_bbox(
    const int* __restrict__ am, const float* __restrict__ logits,
    const float* __restrict__ pd, const float* __restrict__ td,
    float* __restrict__ partial)
{
    __shared__ float red[256];
    const int t = threadIdx.x;
    float s = 0.0f;
    if (blockIdx.x == 0) {
        for (int i = t; i < N_POSA; i += 256) {
            const int tgt = am[i];
            const float l0 = logits[(size_t)i*2+0], l1 = logits[(size_t)i*2+1];
            const float m = fmaxf(l0, l1);
            const float lse = logf(expf(l0-m) + expf(l1-m));
            const float lt = (tgt == 0) ? l0 : l1;
            s += (lt - m) - lse;
        }
    } else {
        for (int i = t; i < N_POSA*4; i += 256) {
            const float d = fabsf(pd[i] - td[i]);
            s += (d < 1.0f) ? 0.5f*d*d : d - 0.5f;
        }
    }
    red[t] = s;
    __syncthreads();
    for (int off = 128; off > 0; off >>= 1) {
        if (t < off) red[t] += red[t+off];
        __syncthreads();
    }
    if (t == 0) partial[blockIdx.x] = red[0];
}

__global__ __launch_bounds__(256) void k_final(
    const float* __restrict__ logits, const unsigned long long* __restrict__ key,
    const int* __restrict__ perm, const float* __restrict__ partial,
    float* __restrict__ out2)
{
    __shared__ float red[256];
    const int t = threadIdx.x;
    float s = 0.0f;
    for (int j = t; j < N_POSA; j += 256) {
        const int r = perm[j];
        const unsigned int i = (unsigned int)(key[r] & 0xffffffffu);
        const float l0 = logits[(size_t)(N_POSA+i)*2+0];
        const float l1 = logits[(size_t)(N_POSA+i)*2+1];
        const float m = fmaxf(l0, l1);
        s += (l0 - m) - logf(expf(l0-m) + expf(l1-m));
    }
    red[t] = s;
    __syncthreads();
    for (int off = 128; off > 0; off >>= 1) {
        if (t < off) red[t] += red[t+off];
        __syncthreads();
    }
    if (t == 0) {
        const float neg_loss = -red[0] / (float)N_POSA;
        const float pos_loss = -partial[0] / (float)N_POSA;
        out2[0] = 0.5f * (pos_loss + neg_loss);
        out2[1] = partial[1] / (float)(N_POSA*4);
    }
}

// ---------------------------------------------------------------------------
// host: exact replication of jax.random.permutation(key(1), 20000)[:1000]
// (threefry2x32, 2 rounds of stable sort-by-random-keys)
// ---------------------------------------------------------------------------
static inline uint32_t rotl32(uint32_t v, int r) { return (v << r) | (v >> (32-r)); }

static void threefry2x32_block(uint32_t k0, uint32_t k1, uint32_t& x0, uint32_t& x1)
{
    const uint32_t ks2 = k0 ^ k1 ^ 0x1BD11BDAu;
    static const int R0[4] = {13,15,26,6};
    static const int R1[4] = {17,29,16,24};
    x0 += k0; x1 += k1;
    for (int r = 0; r < 4; ++r) { x0 += x1; x1 = rotl32(x1, R0[r]); x1 ^= x0; }
    x0 += k1;  x1 += ks2 + 1u;
    for (int r = 0; r < 4; ++r) { x0 += x1; x1 = rotl32(x1, R1[r]); x1 ^= x0; }
    x0 += ks2; x1 += k0 + 2u;
    for (int r = 0; r < 4; ++r) { x0 += x1; x1 = rotl32(x1, R0[r]); x1 ^= x0; }
    x0 += k0;  x1 += k1 + 3u;
    for (int r = 0; r < 4; ++r) { x0 += x1; x1 = rotl32(x1, R1[r]); x1 ^= x0; }
    x0 += k1;  x1 += ks2 + 4u;
    for (int r = 0; r < 4; ++r) { x0 += x1; x1 = rotl32(x1, R0[r]); x1 ^= x0; }
    x0 += ks2; x1 += k0 + 5u;
}

static void compute_perm_host(int* perm1000)
{
    uint32_t k0 = 0u, k1 = 1u;   // jax.random.key(1) -> [seed>>32, seed&0xffffffff]
    std::vector<int> x(POOLN);
    std::iota(x.begin(), x.end(), 0);
    std::vector<uint32_t> bits(POOLN);
    std::vector<int> ord(POOLN);
    for (int round = 0; round < 2; ++round) {   // num_rounds = ceil(3*ln(20000)/ln(2^32-1)) = 2
        // split(key): threefry over iota(4); pairs (0,2) and (1,3)
        uint32_t a0 = 0u, a1 = 2u; threefry2x32_block(k0, k1, a0, a1);
        uint32_t b0 = 1u, b1 = 3u; threefry2x32_block(k0, k1, b0, b1);
        k0 = a0; k1 = b0;                  // new key = first output words
        const uint32_t s0 = a1, s1 = b1;   // subkey  = second output words
        // random_bits(subkey, 32, (20000,)): pairs (i, 10000+i)
        const int half = POOLN/2;
        for (int i = 0; i < half; ++i) {
            uint32_t y0 = (uint32_t)i, y1 = (uint32_t)(half + i);
            threefry2x32_block(s0, s1, y0, y1);
            bits[i] = y0; bits[half+i] = y1;
        }
        std::iota(ord.begin(), ord.end(), 0);
        std::stable_sort(ord.begin(), ord.end(),
                         [&](int A, int B) { return bits[A] < bits[B]; });
        std::vector<int> nx(POOLN);
        for (int i = 0; i < POOLN; ++i) nx[i] = x[ord[i]];
        x.swap(nx);
    }
    std::memcpy(perm1000, x.data(), N_POSA*sizeof(int));
}

// ---------------------------------------------------------------------------
extern "C" void kernel_launch(void* const* d_in, const int* in_sizes, int n_in,
                              void* d_out, int out_size, void* d_ws, size_t ws_size,
                              hipStream_t stream)
{
    const float* f0     = (const float*)d_in[0];
    const float* f1     = (const float*)d_in[1];
    const float* f2     = (const float*)d_in[2];
    const float* f3     = (const float*)d_in[3];
    const float* rois   = (const float*)d_in[4];
    const int*   am     = (const int*)  d_in[5];
    const float* logits = (const float*)d_in[6];
    const float* pd     = (const float*)d_in[7];
    const float* td     = (const float*)d_in[8];
    float* out = (float*)d_out;

    char* ws = (char*)d_ws;
    unsigned long long* key64 = (unsigned long long*)ws;       // 262144 B (born after hist dies)
    unsigned int*       hist  = (unsigned int*)ws;             // 262144 B (aliases key64)
    unsigned int*       sel   = (unsigned int*)(ws + 262144);  // 8 B: [B, counter]
    float*              prt   = (float*)(ws + 262160);         // 8 B: [pos_sum, bbox_sum]
    int*                dperm = (int*)(ws + 262176);           // 4000 B

    static int h_perm[N_POSA];
    compute_perm_host(h_perm);
    hipMemcpyAsync(dperm, h_perm, N_POSA*sizeof(int), hipMemcpyHostToDevice, stream);

    k_roi<<<NROIS, 256, 0, stream>>>(f0, f1, f2, f3, rois, out);

    hipMemsetAsync(hist, 0, 65536*sizeof(unsigned int), stream);
    k_hist<<<(N_NEGA+255)/256, 256, 0, stream>>>(logits, hist);
    k_scan<<<1, 1024, 0, stream>>>(hist, sel);
    k_initkeys<<<SORTN/256, 256, 0, stream>>>(key64);
    k_fill<<<(N_NEGA+255)/256, 256, 0, stream>>>(logits, sel, key64);

    k_sort_local<<<SORTN/LCHUNK, 1024, 0, stream>>>(key64);
    for (int ksz = 2*LCHUNK; ksz <= SORTN; ksz <<= 1) {
        for (int j = ksz >> 1; j >= LCHUNK; j >>= 1)
            k_sort_global<<<(SORTN/2+255)/256, 256, 0, stream>>>(key64, ksz, j);
        k_sort_merge<<<SORTN/LCHUNK, 1024, 0, stream>>>(key64, ksz);
    }

    k_pos_bbox<<<2, 256, 0, stream>>>(am, logits, pd, td, prt);
    k_final<<<1, 256, 0, stream>>>(logits, key64, dperm, prt,
                                   out + (size_t)NROIS*NCH*NBINS);
}

// Round 2
// 299.408 us; speedup vs baseline: 6.6274x; 6.6274x over previous
//
#include <hip/hip_runtime.h>
#include <cstdint>

#define NROIS  4000
#define NCH    128
#define NBINS  49
#define N_POSA 1000
#define N_NEGA 200000
#define POOLN  20000
#define SORTN  32768
#define TOTSORT (3*SORTN)
#define LCHUNK 4096

// tl (channels-last fmaps) float offsets per level
#define L0OFF 0ull
#define L1OFF 16777216ull
#define L2OFF 20971520ull
#define L3OFF 22020096ull
#define TLFLOATS 22282240ull

// ---------------------------------------------------------------------------
// NCHW -> NHWC transpose, per level. in: [B][128][HW], out: [B][HW][128]
// ---------------------------------------------------------------------------
__global__ __launch_bounds__(256) void k_tr(const float* __restrict__ in,
                                            float* __restrict__ out, int HW)
{
    __shared__ float s[32][33];
    const int tx = threadIdx.x, ty = threadIdx.y;
    const int hw0 = blockIdx.x * 32, c0 = blockIdx.y * 32;
    const float* inb = in  + (size_t)blockIdx.z * 128 * HW;
    float*      outb = out + (size_t)blockIdx.z * HW * 128;
#pragma unroll
    for (int j = 0; j < 32; j += 8)
        s[ty + j][tx] = inb[(size_t)(c0 + ty + j) * HW + hw0 + tx];
    __syncthreads();
#pragma unroll
    for (int j = 0; j < 32; j += 8)
        outb[(size_t)(hw0 + ty + j) * 128 + c0 + tx] = s[tx][ty + j];
}

// ---------------------------------------------------------------------------
// ROI align on channels-last fmaps. One block per ROI.
// ---------------------------------------------------------------------------
__global__ __launch_bounds__(256) void k_roi_cl(
    const float* __restrict__ tl, const float* __restrict__ rois,
    float* __restrict__ out)
{
    __shared__ int   s_a[NBINS][4];
    __shared__ float s_w[NBINS][4];
    __shared__ float s_o[NCH * NBINS];   // [c][bin]
    const int n   = blockIdx.x;
    const int tid = threadIdx.x;

    const float ry1 = rois[n*5+0], rx1 = rois[n*5+1];
    const float ry2 = rois[n*5+2], rx2 = rois[n*5+3];
    const int   b   = (int)rois[n*5+4];
    const float h = ry2 - ry1, w = rx2 - rx1;
    const float lraw = rintf(4.0f + log2f(sqrtf(h*w + 1e-12f)));
    int lvl = (int)lraw; lvl = lvl < 0 ? 0 : (lvl > 3 ? 3 : lvl);
    const int H = 256 >> lvl;
    size_t lbase = (lvl == 0) ? L0OFF : (lvl == 1) ? L1OFF : (lvl == 2) ? L2OFF : L3OFF;
    const float* bp = tl + lbase + (size_t)b * (size_t)(H*H) * NCH;

    const float Hf  = (float)H;
    const float y1p = ry1*Hf, x1p = rx1*Hf, y2p = ry2*Hf, x2p = rx2*Hf;
    const float bh = (y2p - y1p) / 7.0f, bw = (x2p - x1p) / 7.0f;

    if (tid < NBINS) {
        const int py = tid / 7, px = tid % 7;
        float sy = y1p + bh*((float)py + 0.5f);
        float sx = x1p + bw*((float)px + 0.5f);
        sy = fminf(fmaxf(sy, 0.0f), Hf - 1.0f);
        sx = fminf(fmaxf(sx, 0.0f), Hf - 1.0f);
        const float y0f = floorf(sy), x0f = floorf(sx);
        const int y0 = (int)y0f, x0 = (int)x0f;
        const int y1i = min(y0+1, H-1), x1i = min(x0+1, H-1);
        const float wy = sy - y0f, wx = sx - x0f;
        s_a[tid][0] = y0 *H + x0;
        s_a[tid][1] = y0 *H + x1i;
        s_a[tid][2] = y1i*H + x0;
        s_a[tid][3] = y1i*H + x1i;
        const float omy = 1.0f - wy, omx = 1.0f - wx;
        s_w[tid][0] = omy*omx; s_w[tid][1] = omy*wx;
        s_w[tid][2] = wy *omx; s_w[tid][3] = wy *wx;
    }
    __syncthreads();

    const int c2 = tid & 63;          // channel pair 0..63
    const int b0 = tid >> 6;          // 0..3
    for (int bin = b0; bin < NBINS; bin += 4) {
        float2 acc = make_float2(0.0f, 0.0f);
#pragma unroll
        for (int tap = 0; tap < 4; ++tap) {
            const float2 v = *(const float2*)(bp + (size_t)s_a[bin][tap] * NCH + 2*c2);
            const float wgt = s_w[bin][tap];
            acc.x += v.x * wgt; acc.y += v.y * wgt;
        }
        s_o[(2*c2)   * NBINS + bin] = acc.x;
        s_o[(2*c2+1) * NBINS + bin] = acc.y;
    }
    __syncthreads();

    float4* outn = (float4*)(out + (size_t)n * (NCH*NBINS));
    const float4* so4 = (const float4*)s_o;
    for (int t4 = tid; t4 < (NCH*NBINS)/4; t4 += 256)
        outn[t4] = so4[t4];
}

// ---------------------------------------------------------------------------
// Fallback ROI align (NCHW direct), used if ws too small for transpose.
// ---------------------------------------------------------------------------
__global__ __launch_bounds__(256) void k_roi(
    const float* __restrict__ f0, const float* __restrict__ f1,
    const float* __restrict__ f2, const float* __restrict__ f3,
    const float* __restrict__ rois, float* __restrict__ out)
{
    __shared__ int   s_a[NBINS][4];
    __shared__ float s_w[NBINS][4];
    const int n   = blockIdx.x;
    const int tid = threadIdx.x;

    const float ry1 = rois[n*5+0], rx1 = rois[n*5+1];
    const float ry2 = rois[n*5+2], rx2 = rois[n*5+3];
    const int   b   = (int)rois[n*5+4];
    const float h = ry2 - ry1, w = rx2 - rx1;
    const float lraw = rintf(4.0f + log2f(sqrtf(h*w + 1e-12f)));
    int lvl = (int)lraw; lvl = lvl < 0 ? 0 : (lvl > 3 ? 3 : lvl);
    const int H = 256 >> lvl;
    const float* f = (lvl==0) ? f0 : (lvl==1) ? f1 : (lvl==2) ? f2 : f3;

    const float Hf  = (float)H;
    const float y1p = ry1*Hf, x1p = rx1*Hf, y2p = ry2*Hf, x2p = rx2*Hf;
    const float bh = (y2p - y1p) / 7.0f, bw = (x2p - x1p) / 7.0f;

    if (tid < NBINS) {
        const int py = tid / 7, px = tid % 7;
        float sy = y1p + bh*((float)py + 0.5f);
        float sx = x1p + bw*((float)px + 0.5f);
        sy = fminf(fmaxf(sy, 0.0f), Hf - 1.0f);
        sx = fminf(fmaxf(sx, 0.0f), Hf - 1.0f);
        const float y0f = floorf(sy), x0f = floorf(sx);
        const int y0 = (int)y0f, x0 = (int)x0f;
        const int y1i = min(y0+1, H-1), x1i = min(x0+1, H-1);
        const float wy = sy - y0f, wx = sx - x0f;
        s_a[tid][0] = y0 *H + x0;
        s_a[tid][1] = y0 *H + x1i;
        s_a[tid][2] = y1i*H + x0;
        s_a[tid][3] = y1i*H + x1i;
        const float omy = 1.0f - wy, omx = 1.0f - wx;
        s_w[tid][0] = omy*omx; s_w[tid][1] = omy*wx;
        s_w[tid][2] = wy *omx; s_w[tid][3] = wy *wx;
    }
    __syncthreads();

    const int hw = H*H;
    const float* basep = f + (size_t)b * NCH * hw;
    float* outn = out + (size_t)n * (NCH*NBINS);
    for (int t = tid; t < NCH*NBINS; t += 256) {
        const int c   = t / NBINS;
        const int bin = t - c*NBINS;
        const float* p = basep + (size_t)c * hw;
        outn[t] = p[s_a[bin][0]]*s_w[bin][0] + p[s_a[bin][1]]*s_w[bin][1]
                + p[s_a[bin][2]]*s_w[bin][2] + p[s_a[bin][3]]*s_w[bin][3];
    }
}

// ---------------------------------------------------------------------------
// threefry2x32 (device) — exact JAX semantics
// ---------------------------------------------------------------------------
__device__ __forceinline__ uint32_t rotl32d(uint32_t v, int r) { return (v << r) | (v >> (32-r)); }

__device__ void tf2x32(uint32_t k0, uint32_t k1, uint32_t& x0, uint32_t& x1)
{
    const uint32_t ks2 = k0 ^ k1 ^ 0x1BD11BDAu;
    const int R0[4] = {13,15,26,6};
    const int R1[4] = {17,29,16,24};
    x0 += k0; x1 += k1;
#pragma unroll
    for (int r = 0; r < 4; ++r) { x0 += x1; x1 = rotl32d(x1, R0[r]); x1 ^= x0; }
    x0 += k1;  x1 += ks2 + 1u;
#pragma unroll
    for (int r = 0; r < 4; ++r) { x0 += x1; x1 = rotl32d(x1, R1[r]); x1 ^= x0; }
    x0 += ks2; x1 += k0 + 2u;
#pragma unroll
    for (int r = 0; r < 4; ++r) { x0 += x1; x1 = rotl32d(x1, R0[r]); x1 ^= x0; }
    x0 += k0;  x1 += k1 + 3u;
#pragma unroll
    for (int r = 0; r < 4; ++r) { x0 += x1; x1 = rotl32d(x1, R1[r]); x1 ^= x0; }
    x0 += k1;  x1 += ks2 + 4u;
#pragma unroll
    for (int r = 0; r < 4; ++r) { x0 += x1; x1 = rotl32d(x1, R0[r]); x1 ^= x0; }
    x0 += ks2; x1 += k0 + 5u;
}

// init pad for all 3 sort arrays + fill perm round-1/round-2 keys
__global__ void k_permfill(unsigned long long* __restrict__ A,
                           unsigned long long* __restrict__ P1,
                           unsigned long long* __restrict__ P2)
{
    const int i = blockIdx.x*256 + threadIdx.x;   // 16384 threads
    if (i < SORTN/2) { A[i] = ~0ull; A[i + SORTN/2] = ~0ull; }
    if (i < SORTN - POOLN) { P1[POOLN + i] = ~0ull; P2[POOLN + i] = ~0ull; }
    if (i < POOLN/2) {
        // key(1) = (0,1); split -> newkey (a0,b0), subkey s1 (a1,b1)
        uint32_t a0 = 0u, a1 = 2u; tf2x32(0u, 1u, a0, a1);
        uint32_t b0 = 1u, b1 = 3u; tf2x32(0u, 1u, b0, b1);
        // split(newkey) -> subkey s2
        uint32_t c0 = 0u, c1 = 2u; tf2x32(a0, b0, c0, c1);
        uint32_t d0 = 1u, d1 = 3u; tf2x32(a0, b0, d0, d1);
        uint32_t x0 = (uint32_t)i, x1 = (uint32_t)(POOLN/2 + i);
        tf2x32(a1, b1, x0, x1);
        P1[i]           = ((unsigned long long)x0 << 32) | (unsigned)i;
        P1[POOLN/2 + i] = ((unsigned long long)x1 << 32) | (unsigned)(POOLN/2 + i);
        uint32_t y0 = (uint32_t)i, y1 = (uint32_t)(POOLN/2 + i);
        tf2x32(c1, d1, y0, y1);
        P2[i]           = ((unsigned long long)y0 << 32) | (unsigned)i;
        P2[POOLN/2 + i] = ((unsigned long long)y1 << 32) | (unsigned)(POOLN/2 + i);
    }
}

// ---------------------------------------------------------------------------
// OHEM select: histogram on monotone bits of d = l0 - l1
// ---------------------------------------------------------------------------
__device__ __forceinline__ unsigned int monobits(float x) {
    unsigned int u = __float_as_uint(x);
    return (u & 0x80000000u) ? ~u : (u | 0x80000000u);
}

__global__ void k_hist(const float* __restrict__ logits, unsigned int* __restrict__ hist)
{
    const int i = blockIdx.x*256 + threadIdx.x;
    if (i >= N_NEGA) return;
    const float l0 = logits[(size_t)(N_POSA+i)*2+0];
    const float l1 = logits[(size_t)(N_POSA+i)*2+1];
    atomicAdd(&hist[monobits(l0 - l1) >> 16], 1u);
}

__global__ __launch_bounds__(1024) void k_scan(const unsigned int* __restrict__ hist,
                                               unsigned int* __restrict__ sel)
{
    __shared__ unsigned int part[1024];
    const int t = threadIdx.x;
    unsigned int s = 0;
    for (int k = 0; k < 64; ++k) s += hist[t*64+k];
    part[t] = s;
    __syncthreads();
    for (int off = 1; off < 1024; off <<= 1) {
        unsigned int v = (t >= off) ? part[t-off] : 0u;
        __syncthreads();
        part[t] += v;
        __syncthreads();
    }
    const unsigned int prev = (t == 0) ? 0u : part[t-1];
    if (prev < POOLN && part[t] >= POOLN) {
        unsigned int run = prev;
        int B = t*64;
        for (int k = 0; k < 64; ++k) {
            run += hist[t*64+k];
            if (run >= POOLN) { B = t*64+k; break; }
        }
        sel[0] = (unsigned int)B;
    }
    if (t == 0) sel[1] = 0u;
}

__global__ void k_fill(const float* __restrict__ logits, unsigned int* __restrict__ sel,
                       unsigned long long* __restrict__ key)
{
    const int i = blockIdx.x*256 + threadIdx.x;
    bool pred = false;
    unsigned int bits = 0;
    if (i < N_NEGA) {
        const float l0 = logits[(size_t)(N_POSA+i)*2+0];
        const float l1 = logits[(size_t)(N_POSA+i)*2+1];
        bits = monobits(l0 - l1);
        pred = (bits >> 16) <= sel[0];
    }
    const unsigned long long mask = __ballot(pred);
    if (!pred) return;
    const int lane = threadIdx.x & 63;
    const int off  = __popcll(mask & ((1ull << lane) - 1ull));
    const int leader = __ffsll((long long)mask) - 1;
    unsigned int base = 0;
    if (lane == leader) base = atomicAdd(&sel[1], (unsigned)__popcll(mask));
    base = __shfl(base, leader);
    const unsigned int pos = base + off;
    if (pos < SORTN) key[pos] = ((unsigned long long)bits << 32) | (unsigned)i;
}

// ---------------------------------------------------------------------------
// Bitonic sort over 3 concatenated 32768-element arrays (direction uses
// index within each array: idx & (SORTN-1)).
// ---------------------------------------------------------------------------
__global__ __launch_bounds__(1024) void k_sort_local(unsigned long long* __restrict__ key)
{
    __shared__ unsigned long long s[LCHUNK];
    const int t = threadIdx.x;
    const int base = blockIdx.x * LCHUNK;
    for (int k = t; k < LCHUNK; k += 1024) s[k] = key[base+k];
    __syncthreads();
    for (int ksz = 2; ksz <= LCHUNK; ksz <<= 1) {
        for (int j = ksz>>1; j >= 1; j >>= 1) {
            for (int p = t; p < LCHUNK/2; p += 1024) {
                const int i = ((p & ~(j-1)) << 1) | (p & (j-1));
                const int l = i | j;
                const bool up = ((((base + i) & (SORTN-1)) & ksz) == 0);
                unsigned long long a = s[i], b = s[l];
                if ((a > b) == up) { s[i] = b; s[l] = a; }
            }
            __syncthreads();
        }
    }
    for (int k = t; k < LCHUNK; k += 1024) key[base+k] = s[k];
}

__global__ void k_sort_global(unsigned long long* __restrict__ key, int ksz, int j)
{
    const int p = blockIdx.x*256 + threadIdx.x;
    if (p >= TOTSORT/2) return;
    const int i = ((p & ~(j-1)) << 1) | (p & (j-1));
    const int l = i | j;
    const bool up = (((i & (SORTN-1)) & ksz) == 0);
    unsigned long long a = key[i], b = key[l];
    if ((a > b) == up) { key[i] = b; key[l] = a; }
}

__global__ __launch_bounds__(1024) void k_sort_merge(unsigned long long* __restrict__ key, int ksz)
{
    __shared__ unsigned long long s[LCHUNK];
    const int t = threadIdx.x;
    const int base = blockIdx.x * LCHUNK;
    for (int k = t; k < LCHUNK; k += 1024) s[k] = key[base+k];
    __syncthreads();
    for (int j = LCHUNK/2; j >= 1; j >>= 1) {
        for (int p = t; p < LCHUNK/2; p += 1024) {
            const int i = ((p & ~(j-1)) << 1) | (p & (j-1));
            const int l = i | j;
            const bool up = ((((base + i) & (SORTN-1)) & ksz) == 0);
            unsigned long long a = s[i], b = s[l];
            if ((a > b) == up) { s[i] = b; s[l] = a; }
        }
        __syncthreads();
    }
    for (int k = t; k < LCHUNK; k += 1024) key[base+k] = s[k];
}

// ---------------------------------------------------------------------------
// losses
// ---------------------------------------------------------------------------
__global__ __launch_bounds__(256) void k_pos_bbox(
    const int* __restrict__ am, const float* __restrict__ logits,
    const float* __restrict__ pd, const float* __restrict__ td,
    float* __restrict__ partial)
{
    __shared__ float red[256];
    const int t = threadIdx.x;
    float s = 0.0f;
    if (blockIdx.x == 0) {
        for (int i = t; i < N_POSA; i += 256) {
            const int tgt = am[i];
            const float l0 = logits[(size_t)i*2+0], l1 = logits[(size_t)i*2+1];
            const float m = fmaxf(l0, l1);
            const float lse = logf(expf(l0-m) + expf(l1-m));
            const float lt = (tgt == 0) ? l0 : l1;
            s += (lt - m) - lse;
        }
    } else {
        for (int i = t; i < N_POSA*4; i += 256) {
            const float d = fabsf(pd[i] - td[i]);
            s += (d < 1.0f) ? 0.5f*d*d : d - 0.5f;
        }
    }
    red[t] = s;
    __syncthreads();
    for (int off = 128; off > 0; off >>= 1) {
        if (t < off) red[t] += red[t+off];
        __syncthreads();
    }
    if (t == 0) partial[blockIdx.x] = red[0];
}

__global__ __launch_bounds__(256) void k_final(
    const float* __restrict__ logits, const unsigned long long* __restrict__ A,
    const unsigned long long* __restrict__ P1, const unsigned long long* __restrict__ P2,
    const float* __restrict__ partial, float* __restrict__ out2)
{
    __shared__ float red[256];
    const int t = threadIdx.x;
    float s = 0.0f;
    for (int j = t; j < N_POSA; j += 256) {
        const int i2 = (int)(unsigned)(P2[j] & 0xffffffffu);   // position after round-2 sort
        const int r  = (int)(unsigned)(P1[i2] & 0xffffffffu);  // perm value
        const unsigned int i = (unsigned)(A[r] & 0xffffffffu); // anchor index in negs
        const float l0 = logits[(size_t)(N_POSA+i)*2+0];
        const float l1 = logits[(size_t)(N_POSA+i)*2+1];
        const float m = fmaxf(l0, l1);
        s += (l0 - m) - logf(expf(l0-m) + expf(l1-m));
    }
    red[t] = s;
    __syncthreads();
    for (int off = 128; off > 0; off >>= 1) {
        if (t < off) red[t] += red[t+off];
        __syncthreads();
    }
    if (t == 0) {
        const float neg_loss = -red[0] / (float)N_POSA;
        const float pos_loss = -partial[0] / (float)N_POSA;
        out2[0] = 0.5f * (pos_loss + neg_loss);
        out2[1] = partial[1] / (float)(N_POSA*4);
    }
}

// ---------------------------------------------------------------------------
extern "C" void kernel_launch(void* const* d_in, const int* in_sizes, int n_in,
                              void* d_out, int out_size, void* d_ws, size_t ws_size,
                              hipStream_t stream)
{
    const float* f0     = (const float*)d_in[0];
    const float* f1     = (const float*)d_in[1];
    const float* f2     = (const float*)d_in[2];
    const float* f3     = (const float*)d_in[3];
    const float* rois   = (const float*)d_in[4];
    const int*   am     = (const int*)  d_in[5];
    const float* logits = (const float*)d_in[6];
    const float* pd     = (const float*)d_in[7];
    const float* td     = (const float*)d_in[8];
    float* out = (float*)d_out;

    char* ws = (char*)d_ws;
    unsigned long long* A    = (unsigned long long*)(ws);            // 262144 B
    unsigned long long* P1   = (unsigned long long*)(ws + 262144);   // 262144 B
    unsigned long long* P2   = (unsigned long long*)(ws + 524288);   // 262144 B
    unsigned int*       hist = (unsigned int*)      (ws + 786432);   // 262144 B
    unsigned int*       sel  = (unsigned int*)      (ws + 1048576);  // 8 B
    float*              prt  = (float*)             (ws + 1048608);  // 8 B
    float*              tl   = (float*)             (ws + 1052672);  // 89128960 B
    const size_t NEED = 1052672ull + TLFLOATS * 4ull;

    // ---- ROI align ----
    if (ws_size >= NEED) {
        k_tr<<<dim3(65536/32, 4, 2), dim3(32,8), 0, stream>>>(f0, tl + L0OFF, 65536);
        k_tr<<<dim3(16384/32, 4, 2), dim3(32,8), 0, stream>>>(f1, tl + L1OFF, 16384);
        k_tr<<<dim3( 4096/32, 4, 2), dim3(32,8), 0, stream>>>(f2, tl + L2OFF,  4096);
        k_tr<<<dim3( 1024/32, 4, 2), dim3(32,8), 0, stream>>>(f3, tl + L3OFF,  1024);
        k_roi_cl<<<NROIS, 256, 0, stream>>>(tl, rois, out);
    } else {
        k_roi<<<NROIS, 256, 0, stream>>>(f0, f1, f2, f3, rois, out);
    }

    // ---- OHEM selection + permutation keys ----
    hipMemsetAsync(hist, 0, 65536*sizeof(unsigned int), stream);
    k_permfill<<<SORTN/2/256, 256, 0, stream>>>(A, P1, P2);
    k_hist<<<(N_NEGA+255)/256, 256, 0, stream>>>(logits, hist);
    k_scan<<<1, 1024, 0, stream>>>(hist, sel);
    k_fill<<<(N_NEGA+255)/256, 256, 0, stream>>>(logits, sel, A);

    // ---- joint bitonic sort of A, P1, P2 (concatenated) ----
    k_sort_local<<<TOTSORT/LCHUNK, 1024, 0, stream>>>(A);
    for (int ksz = 2*LCHUNK; ksz <= SORTN; ksz <<= 1) {
        for (int j = ksz >> 1; j >= LCHUNK; j >>= 1)
            k_sort_global<<<(TOTSORT/2+255)/256, 256, 0, stream>>>(A, ksz, j);
        k_sort_merge<<<TOTSORT/LCHUNK, 1024, 0, stream>>>(A, ksz);
    }

    // ---- losses ----
    k_pos_bbox<<<2, 256, 0, stream>>>(am, logits, pd, td, prt);
    k_final<<<1, 256, 0, stream>>>(logits, A, P1, P2, prt,
                                   out + (size_t)NROIS*NCH*NBINS);
}

// Round 3
// 297.099 us; speedup vs baseline: 6.6789x; 1.0078x over previous
//
#include <hip/hip_runtime.h>
#include <hip/hip_bf16.h>
#include <cstdint>

#define NROIS  4000
#define NCH    128
#define NBINS  49
#define N_POSA 1000
#define N_NEGA 200000
#define POOLN  20000
#define SORTN  32768
#define TOTSORT (3*SORTN)
#define LCHUNK 16384
#define HBITS  12
#define HBINSZ 4096

// tl (channels-last bf16 fmaps) element offsets per level
#define L0OFF 0ull
#define L1OFF 16777216ull
#define L2OFF 20971520ull
#define L3OFF 22020096ull
#define TLELEMS 22282240ull

// ---------------------------------------------------------------------------
// Fused NCHW -> NHWC transpose (f32 -> bf16), all 4 levels in one grid.
// blockIdx.x encodes (level, hw-tile); y = channel tile; z = batch.
// ---------------------------------------------------------------------------
__global__ __launch_bounds__(256) void k_tr(
    const float* __restrict__ f0, const float* __restrict__ f1,
    const float* __restrict__ f2, const float* __restrict__ f3,
    __hip_bfloat16* __restrict__ tl)
{
    __shared__ float s[32][33];
    const int bx = blockIdx.x;
    int lvl, start;
    if      (bx < 2048) { lvl = 0; start = 0;    }
    else if (bx < 2560) { lvl = 1; start = 2048; }
    else if (bx < 2688) { lvl = 2; start = 2560; }
    else                { lvl = 3; start = 2688; }
    const int HW = 65536 >> (2*lvl);
    const float* in = (lvl==0) ? f0 : (lvl==1) ? f1 : (lvl==2) ? f2 : f3;
    const size_t ooff = (lvl==0) ? L0OFF : (lvl==1) ? L1OFF : (lvl==2) ? L2OFF : L3OFF;

    const int tx = threadIdx.x, ty = threadIdx.y;
    const int hw0 = (bx - start) * 32, c0 = blockIdx.y * 32;
    const float* inb = in + (size_t)blockIdx.z * 128 * HW;
    __hip_bfloat16* outb = tl + ooff + (size_t)blockIdx.z * (size_t)HW * 128;
#pragma unroll
    for (int j = 0; j < 32; j += 8)
        s[ty + j][tx] = inb[(size_t)(c0 + ty + j) * HW + hw0 + tx];
    __syncthreads();
#pragma unroll
    for (int j = 0; j < 32; j += 8)
        outb[(size_t)(hw0 + ty + j) * 128 + c0 + tx] = __float2bfloat16(s[tx][ty + j]);
}

// ---------------------------------------------------------------------------
// ROI align on channels-last bf16 fmaps. One block per ROI.
// ---------------------------------------------------------------------------
__global__ __launch_bounds__(256) void k_roi_cl(
    const __hip_bfloat16* __restrict__ tl, const float* __restrict__ rois,
    float* __restrict__ out)
{
    __shared__ int   s_a[NBINS][4];
    __shared__ float s_w[NBINS][4];
    __shared__ float s_o[NCH * NBINS];   // [c][bin]
    const int n   = blockIdx.x;
    const int tid = threadIdx.x;

    const float ry1 = rois[n*5+0], rx1 = rois[n*5+1];
    const float ry2 = rois[n*5+2], rx2 = rois[n*5+3];
    const int   b   = (int)rois[n*5+4];
    const float h = ry2 - ry1, w = rx2 - rx1;
    const float lraw = rintf(4.0f + log2f(sqrtf(h*w + 1e-12f)));
    int lvl = (int)lraw; lvl = lvl < 0 ? 0 : (lvl > 3 ? 3 : lvl);
    const int H = 256 >> lvl;
    const size_t lbase = (lvl==0) ? L0OFF : (lvl==1) ? L1OFF : (lvl==2) ? L2OFF : L3OFF;
    const __hip_bfloat16* bp = tl + lbase + (size_t)b * (size_t)(H*H) * NCH;

    const float Hf  = (float)H;
    const float y1p = ry1*Hf, x1p = rx1*Hf, y2p = ry2*Hf, x2p = rx2*Hf;
    const float bh = (y2p - y1p) / 7.0f, bw = (x2p - x1p) / 7.0f;

    if (tid < NBINS) {
        const int py = tid / 7, px = tid % 7;
        float sy = y1p + bh*((float)py + 0.5f);
        float sx = x1p + bw*((float)px + 0.5f);
        sy = fminf(fmaxf(sy, 0.0f), Hf - 1.0f);
        sx = fminf(fmaxf(sx, 0.0f), Hf - 1.0f);
        const float y0f = floorf(sy), x0f = floorf(sx);
        const int y0 = (int)y0f, x0 = (int)x0f;
        const int y1i = min(y0+1, H-1), x1i = min(x0+1, H-1);
        const float wy = sy - y0f, wx = sx - x0f;
        s_a[tid][0] = y0 *H + x0;
        s_a[tid][1] = y0 *H + x1i;
        s_a[tid][2] = y1i*H + x0;
        s_a[tid][3] = y1i*H + x1i;
        const float omy = 1.0f - wy, omx = 1.0f - wx;
        s_w[tid][0] = omy*omx; s_w[tid][1] = omy*wx;
        s_w[tid][2] = wy *omx; s_w[tid][3] = wy *wx;
    }
    __syncthreads();

    const int c2 = tid & 63;          // channel pair 0..63
    const int b0 = tid >> 6;          // 0..3
    for (int bin = b0; bin < NBINS; bin += 4) {
        float ax = 0.0f, ay = 0.0f;
#pragma unroll
        for (int tap = 0; tap < 4; ++tap) {
            const unsigned int u =
                *(const unsigned int*)(bp + (size_t)s_a[bin][tap] * NCH + 2*c2);
            const float lo = __uint_as_float(u << 16);
            const float hi = __uint_as_float(u & 0xffff0000u);
            const float wgt = s_w[bin][tap];
            ax += lo * wgt; ay += hi * wgt;
        }
        s_o[(2*c2)   * NBINS + bin] = ax;
        s_o[(2*c2+1) * NBINS + bin] = ay;
    }
    __syncthreads();

    float4* outn = (float4*)(out + (size_t)n * (NCH*NBINS));
    const float4* so4 = (const float4*)s_o;
    for (int t4 = tid; t4 < (NCH*NBINS)/4; t4 += 256)
        outn[t4] = so4[t4];
}

// ---------------------------------------------------------------------------
// Fallback ROI align (NCHW direct), used if ws too small for transpose.
// ---------------------------------------------------------------------------
__global__ __launch_bounds__(256) void k_roi(
    const float* __restrict__ f0, const float* __restrict__ f1,
    const float* __restrict__ f2, const float* __restrict__ f3,
    const float* __restrict__ rois, float* __restrict__ out)
{
    __shared__ int   s_a[NBINS][4];
    __shared__ float s_w[NBINS][4];
    const int n   = blockIdx.x;
    const int tid = threadIdx.x;

    const float ry1 = rois[n*5+0], rx1 = rois[n*5+1];
    const float ry2 = rois[n*5+2], rx2 = rois[n*5+3];
    const int   b   = (int)rois[n*5+4];
    const float h = ry2 - ry1, w = rx2 - rx1;
    const float lraw = rintf(4.0f + log2f(sqrtf(h*w + 1e-12f)));
    int lvl = (int)lraw; lvl = lvl < 0 ? 0 : (lvl > 3 ? 3 : lvl);
    const int H = 256 >> lvl;
    const float* f = (lvl==0) ? f0 : (lvl==1) ? f1 : (lvl==2) ? f2 : f3;

    const float Hf  = (float)H;
    const float y1p = ry1*Hf, x1p = rx1*Hf, y2p = ry2*Hf, x2p = rx2*Hf;
    const float bh = (y2p - y1p) / 7.0f, bw = (x2p - x1p) / 7.0f;

    if (tid < NBINS) {
        const int py = tid / 7, px = tid % 7;
        float sy = y1p + bh*((float)py + 0.5f);
        float sx = x1p + bw*((float)px + 0.5f);
        sy = fminf(fmaxf(sy, 0.0f), Hf - 1.0f);
        sx = fminf(fmaxf(sx, 0.0f), Hf - 1.0f);
        const float y0f = floorf(sy), x0f = floorf(sx);
        const int y0 = (int)y0f, x0 = (int)x0f;
        const int y1i = min(y0+1, H-1), x1i = min(x0+1, H-1);
        const float wy = sy - y0f, wx = sx - x0f;
        s_a[tid][0] = y0 *H + x0;
        s_a[tid][1] = y0 *H + x1i;
        s_a[tid][2] = y1i*H + x0;
        s_a[tid][3] = y1i*H + x1i;
        const float omy = 1.0f - wy, omx = 1.0f - wx;
        s_w[tid][0] = omy*omx; s_w[tid][1] = omy*wx;
        s_w[tid][2] = wy *omx; s_w[tid][3] = wy *wx;
    }
    __syncthreads();

    const int hw = H*H;
    const float* basep = f + (size_t)b * NCH * hw;
    float* outn = out + (size_t)n * (NCH*NBINS);
    for (int t = tid; t < NCH*NBINS; t += 256) {
        const int c   = t / NBINS;
        const int bin = t - c*NBINS;
        const float* p = basep + (size_t)c * hw;
        outn[t] = p[s_a[bin][0]]*s_w[bin][0] + p[s_a[bin][1]]*s_w[bin][1]
                + p[s_a[bin][2]]*s_w[bin][2] + p[s_a[bin][3]]*s_w[bin][3];
    }
}

// ---------------------------------------------------------------------------
// threefry2x32 (device) — exact JAX semantics
// ---------------------------------------------------------------------------
__device__ __forceinline__ uint32_t rotl32d(uint32_t v, int r) { return (v << r) | (v >> (32-r)); }

__device__ void tf2x32(uint32_t k0, uint32_t k1, uint32_t& x0, uint32_t& x1)
{
    const uint32_t ks2 = k0 ^ k1 ^ 0x1BD11BDAu;
    const int R0[4] = {13,15,26,6};
    const int R1[4] = {17,29,16,24};
    x0 += k0; x1 += k1;
#pragma unroll
    for (int r = 0; r < 4; ++r) { x0 += x1; x1 = rotl32d(x1, R0[r]); x1 ^= x0; }
    x0 += k1;  x1 += ks2 + 1u;
#pragma unroll
    for (int r = 0; r < 4; ++r) { x0 += x1; x1 = rotl32d(x1, R1[r]); x1 ^= x0; }
    x0 += ks2; x1 += k0 + 2u;
#pragma unroll
    for (int r = 0; r < 4; ++r) { x0 += x1; x1 = rotl32d(x1, R0[r]); x1 ^= x0; }
    x0 += k0;  x1 += k1 + 3u;
#pragma unroll
    for (int r = 0; r < 4; ++r) { x0 += x1; x1 = rotl32d(x1, R1[r]); x1 ^= x0; }
    x0 += k1;  x1 += ks2 + 4u;
#pragma unroll
    for (int r = 0; r < 4; ++r) { x0 += x1; x1 = rotl32d(x1, R0[r]); x1 ^= x0; }
    x0 += ks2; x1 += k0 + 5u;
}

// ---------------------------------------------------------------------------
// k_prep: perm keys + pads + hist zero (blocks 0..63), pos loss (64),
// bbox loss (65).
// ---------------------------------------------------------------------------
__global__ __launch_bounds__(256) void k_prep(
    unsigned long long* __restrict__ A, unsigned long long* __restrict__ P1,
    unsigned long long* __restrict__ P2, unsigned int* __restrict__ hist,
    const int* __restrict__ am, const float* __restrict__ logits,
    const float* __restrict__ pd, const float* __restrict__ td,
    float* __restrict__ prt)
{
    const int bid = blockIdx.x;
    const int t   = threadIdx.x;
    if (bid < 64) {
        const int i = bid*256 + t;                       // 0..16383
        if (i < HBINSZ) hist[i] = 0u;
        A[i] = ~0ull; A[i + SORTN/2] = ~0ull;
        if (i < SORTN - POOLN) { P1[POOLN + i] = ~0ull; P2[POOLN + i] = ~0ull; }
        if (i < POOLN/2) {
            uint32_t a0 = 0u, a1 = 2u; tf2x32(0u, 1u, a0, a1);
            uint32_t b0 = 1u, b1 = 3u; tf2x32(0u, 1u, b0, b1);
            uint32_t c0 = 0u, c1 = 2u; tf2x32(a0, b0, c0, c1);
            uint32_t d0 = 1u, d1 = 3u; tf2x32(a0, b0, d0, d1);
            uint32_t x0 = (uint32_t)i, x1 = (uint32_t)(POOLN/2 + i);
            tf2x32(a1, b1, x0, x1);
            P1[i]           = ((unsigned long long)x0 << 32) | (unsigned)i;
            P1[POOLN/2 + i] = ((unsigned long long)x1 << 32) | (unsigned)(POOLN/2 + i);
            uint32_t y0 = (uint32_t)i, y1 = (uint32_t)(POOLN/2 + i);
            tf2x32(c1, d1, y0, y1);
            P2[i]           = ((unsigned long long)y0 << 32) | (unsigned)i;
            P2[POOLN/2 + i] = ((unsigned long long)y1 << 32) | (unsigned)(POOLN/2 + i);
        }
        return;
    }
    __shared__ float red[256];
    float s = 0.0f;
    if (bid == 64) {
        for (int i = t; i < N_POSA; i += 256) {
            const int tgt = am[i];
            const float l0 = logits[(size_t)i*2+0], l1 = logits[(size_t)i*2+1];
            const float m = fmaxf(l0, l1);
            const float lse = logf(expf(l0-m) + expf(l1-m));
            const float lt = (tgt == 0) ? l0 : l1;
            s += (lt - m) - lse;
        }
    } else {
        for (int i = t; i < N_POSA*4; i += 256) {
            const float d = fabsf(pd[i] - td[i]);
            s += (d < 1.0f) ? 0.5f*d*d : d - 0.5f;
        }
    }
    red[t] = s;
    __syncthreads();
    for (int off = 128; off > 0; off >>= 1) {
        if (t < off) red[t] += red[t+off];
        __syncthreads();
    }
    if (t == 0) prt[bid - 64] = red[0];
}

// ---------------------------------------------------------------------------
// OHEM histogram: 12-bit bins, per-block LDS aggregation.
// ---------------------------------------------------------------------------
__device__ __forceinline__ unsigned int monobits(float x) {
    unsigned int u = __float_as_uint(x);
    return (u & 0x80000000u) ? ~u : (u | 0x80000000u);
}

__global__ __launch_bounds__(256) void k_hist(const float* __restrict__ logits,
                                              unsigned int* __restrict__ hist)
{
    __shared__ unsigned int lh[HBINSZ];
    const int t = threadIdx.x;
    for (int b = t; b < HBINSZ; b += 256) lh[b] = 0u;
    __syncthreads();
    for (int i = blockIdx.x*256 + t; i < N_NEGA; i += 64*256) {
        const float l0 = logits[(size_t)(N_POSA+i)*2+0];
        const float l1 = logits[(size_t)(N_POSA+i)*2+1];
        atomicAdd(&lh[monobits(l0 - l1) >> (32-HBITS)], 1u);
    }
    __syncthreads();
    for (int b = t; b < HBINSZ; b += 256) {
        const unsigned int v = lh[b];
        if (v) atomicAdd(&hist[b], v);
    }
}

__global__ __launch_bounds__(1024) void k_scan(const unsigned int* __restrict__ hist,
                                               unsigned int* __restrict__ sel)
{
    __shared__ unsigned int part[1024];
    const int t = threadIdx.x;
    unsigned int s = 0;
    for (int k = 0; k < HBINSZ/1024; ++k) s += hist[t*(HBINSZ/1024)+k];
    part[t] = s;
    __syncthreads();
    for (int off = 1; off < 1024; off <<= 1) {
        unsigned int v = (t >= off) ? part[t-off] : 0u;
        __syncthreads();
        part[t] += v;
        __syncthreads();
    }
    const unsigned int prev = (t == 0) ? 0u : part[t-1];
    if (prev < POOLN && part[t] >= POOLN) {
        unsigned int run = prev;
        int B = t*(HBINSZ/1024);
        for (int k = 0; k < HBINSZ/1024; ++k) {
            run += hist[t*(HBINSZ/1024)+k];
            if (run >= POOLN) { B = t*(HBINSZ/1024)+k; break; }
        }
        sel[0] = (unsigned int)B;
    }
    if (t == 0) sel[1] = 0u;
}

__global__ void k_fill(const float* __restrict__ logits, unsigned int* __restrict__ sel,
                       unsigned long long* __restrict__ key)
{
    const int i = blockIdx.x*256 + threadIdx.x;
    bool pred = false;
    unsigned int bits = 0;
    if (i < N_NEGA) {
        const float l0 = logits[(size_t)(N_POSA+i)*2+0];
        const float l1 = logits[(size_t)(N_POSA+i)*2+1];
        bits = monobits(l0 - l1);
        pred = (bits >> (32-HBITS)) <= sel[0];
    }
    const unsigned long long mask = __ballot(pred);
    if (!pred) return;
    const int lane = threadIdx.x & 63;
    const int off  = __popcll(mask & ((1ull << lane) - 1ull));
    const int leader = __ffsll((long long)mask) - 1;
    unsigned int base = 0;
    if (lane == leader) base = atomicAdd(&sel[1], (unsigned)__popcll(mask));
    base = __shfl(base, leader);
    const unsigned int pos = base + off;
    if (pos < SORTN) key[pos] = ((unsigned long long)bits << 32) | (unsigned)i;
}

// ---------------------------------------------------------------------------
// Bitonic sort over 3 concatenated 32768-element arrays.
// LCHUNK=16384 (128 KiB LDS) -> 3 dispatches total.
// ---------------------------------------------------------------------------
__global__ __launch_bounds__(1024) void k_sort_local(unsigned long long* __restrict__ key)
{
    __shared__ unsigned long long s[LCHUNK];
    const int t = threadIdx.x;
    const int base = blockIdx.x * LCHUNK;
    for (int k = t; k < LCHUNK; k += 1024) s[k] = key[base+k];
    __syncthreads();
    for (int ksz = 2; ksz <= LCHUNK; ksz <<= 1) {
        for (int j = ksz>>1; j >= 1; j >>= 1) {
            for (int p = t; p < LCHUNK/2; p += 1024) {
                const int i = ((p & ~(j-1)) << 1) | (p & (j-1));
                const int l = i | j;
                const bool up = ((((base + i) & (SORTN-1)) & ksz) == 0);
                unsigned long long a = s[i], b = s[l];
                if ((a > b) == up) { s[i] = b; s[l] = a; }
            }
            __syncthreads();
        }
    }
    for (int k = t; k < LCHUNK; k += 1024) key[base+k] = s[k];
}

__global__ void k_sort_global(unsigned long long* __restrict__ key, int ksz, int j)
{
    const int p = blockIdx.x*256 + threadIdx.x;
    if (p >= TOTSORT/2) return;
    const int i = ((p & ~(j-1)) << 1) | (p & (j-1));
    const int l = i | j;
    const bool up = (((i & (SORTN-1)) & ksz) == 0);
    unsigned long long a = key[i], b = key[l];
    if ((a > b) == up) { key[i] = b; key[l] = a; }
}

__global__ __launch_bounds__(1024) void k_sort_merge(unsigned long long* __restrict__ key, int ksz)
{
    __shared__ unsigned long long s[LCHUNK];
    const int t = threadIdx.x;
    const int base = blockIdx.x * LCHUNK;
    for (int k = t; k < LCHUNK; k += 1024) s[k] = key[base+k];
    __syncthreads();
    for (int j = LCHUNK/2; j >= 1; j >>= 1) {
        for (int p = t; p < LCHUNK/2; p += 1024) {
            const int i = ((p & ~(j-1)) << 1) | (p & (j-1));
            const int l = i | j;
            const bool up = ((((base + i) & (SORTN-1)) & ksz) == 0);
            unsigned long long a = s[i], b = s[l];
            if ((a > b) == up) { s[i] = b; s[l] = a; }
        }
        __syncthreads();
    }
    for (int k = t; k < LCHUNK; k += 1024) key[base+k] = s[k];
}

// ---------------------------------------------------------------------------
__global__ __launch_bounds__(256) void k_final(
    const float* __restrict__ logits, const unsigned long long* __restrict__ A,
    const unsigned long long* __restrict__ P1, const unsigned long long* __restrict__ P2,
    const float* __restrict__ partial, float* __restrict__ out2)
{
    __shared__ float red[256];
    const int t = threadIdx.x;
    float s = 0.0f;
    for (int j = t; j < N_POSA; j += 256) {
        const int i2 = (int)(unsigned)(P2[j] & 0xffffffffu);
        const int r  = (int)(unsigned)(P1[i2] & 0xffffffffu);
        const unsigned int i = (unsigned)(A[r] & 0xffffffffu);
        const float l0 = logits[(size_t)(N_POSA+i)*2+0];
        const float l1 = logits[(size_t)(N_POSA+i)*2+1];
        const float m = fmaxf(l0, l1);
        s += (l0 - m) - logf(expf(l0-m) + expf(l1-m));
    }
    red[t] = s;
    __syncthreads();
    for (int off = 128; off > 0; off >>= 1) {
        if (t < off) red[t] += red[t+off];
        __syncthreads();
    }
    if (t == 0) {
        const float neg_loss = -red[0] / (float)N_POSA;
        const float pos_loss = -partial[0] / (float)N_POSA;
        out2[0] = 0.5f * (pos_loss + neg_loss);
        out2[1] = partial[1] / (float)(N_POSA*4);
    }
}

// ---------------------------------------------------------------------------
extern "C" void kernel_launch(void* const* d_in, const int* in_sizes, int n_in,
                              void* d_out, int out_size, void* d_ws, size_t ws_size,
                              hipStream_t stream)
{
    const float* f0     = (const float*)d_in[0];
    const float* f1     = (const float*)d_in[1];
    const float* f2     = (const float*)d_in[2];
    const float* f3     = (const float*)d_in[3];
    const float* rois   = (const float*)d_in[4];
    const int*   am     = (const int*)  d_in[5];
    const float* logits = (const float*)d_in[6];
    const float* pd     = (const float*)d_in[7];
    const float* td     = (const float*)d_in[8];
    float* out = (float*)d_out;

    char* ws = (char*)d_ws;
    unsigned long long* A    = (unsigned long long*)(ws);            // 262144 B
    unsigned long long* P1   = (unsigned long long*)(ws + 262144);   // 262144 B
    unsigned long long* P2   = (unsigned long long*)(ws + 524288);   // 262144 B
    unsigned int*       hist = (unsigned int*)      (ws + 786432);   // 16384 B
    unsigned int*       sel  = (unsigned int*)      (ws + 802816);   // 8 B
    float*              prt  = (float*)             (ws + 802848);   // 8 B
    __hip_bfloat16*     tl   = (__hip_bfloat16*)    (ws + 1052672);  // 44564480 B
    const size_t NEED = 1052672ull + TLELEMS * 2ull;

    // ---- losses prep (also zeroes hist) ----
    k_prep<<<66, 256, 0, stream>>>(A, P1, P2, hist, am, logits, pd, td, prt);

    // ---- ROI align ----
    if (ws_size >= NEED) {
        k_tr<<<dim3(2720, 4, 2), dim3(32,8), 0, stream>>>(f0, f1, f2, f3, tl);
        k_roi_cl<<<NROIS, 256, 0, stream>>>(tl, rois, out);
    } else {
        k_roi<<<NROIS, 256, 0, stream>>>(f0, f1, f2, f3, rois, out);
    }

    // ---- OHEM selection ----
    k_hist<<<64, 256, 0, stream>>>(logits, hist);
    k_scan<<<1, 1024, 0, stream>>>(hist, sel);
    k_fill<<<(N_NEGA+255)/256, 256, 0, stream>>>(logits, sel, A);

    // ---- joint bitonic sort of A, P1, P2 ----
    k_sort_local<<<TOTSORT/LCHUNK, 1024, 0, stream>>>(A);
    k_sort_global<<<(TOTSORT/2+255)/256, 256, 0, stream>>>(A, SORTN, LCHUNK);
    k_sort_merge<<<TOTSORT/LCHUNK, 1024, 0, stream>>>(A, SORTN);

    // ---- final scalars ----
    k_final<<<1, 256, 0, stream>>>(logits, A, P1, P2, prt,
                                   out + (size_t)NROIS*NCH*NBINS);
}

// Round 4
// 203.285 us; speedup vs baseline: 9.7611x; 1.4615x over previous
//
#include <hip/hip_runtime.h>
#include <hip/hip_bf16.h>
#include <cstdint>

#define NROIS  4000
#define NCH    128
#define NBINS  49
#define N_POSA 1000
#define N_NEGA 200000
#define POOLN  20000
#define HBITS_A 13
#define ABINS  8192
#define PBINS  4096
#define ACAP   8192

// tl (channels-last bf16 fmaps) element offsets per level
#define L0OFF 0ull
#define L1OFF 16777216ull
#define L2OFF 20971520ull
#define L3OFF 22020096ull
#define TLELEMS 22282240ull

// ---------------------------------------------------------------------------
// Fused NCHW -> NHWC transpose (f32 -> bf16), all 4 levels in one grid.
// ---------------------------------------------------------------------------
__global__ __launch_bounds__(256) void k_tr(
    const float* __restrict__ f0, const float* __restrict__ f1,
    const float* __restrict__ f2, const float* __restrict__ f3,
    __hip_bfloat16* __restrict__ tl)
{
    __shared__ float s[32][33];
    const int bx = blockIdx.x;
    int lvl, start;
    if      (bx < 2048) { lvl = 0; start = 0;    }
    else if (bx < 2560) { lvl = 1; start = 2048; }
    else if (bx < 2688) { lvl = 2; start = 2560; }
    else                { lvl = 3; start = 2688; }
    const int HW = 65536 >> (2*lvl);
    const float* in = (lvl==0) ? f0 : (lvl==1) ? f1 : (lvl==2) ? f2 : f3;
    const size_t ooff = (lvl==0) ? L0OFF : (lvl==1) ? L1OFF : (lvl==2) ? L2OFF : L3OFF;

    const int tx = threadIdx.x, ty = threadIdx.y;
    const int hw0 = (bx - start) * 32, c0 = blockIdx.y * 32;
    const float* inb = in + (size_t)blockIdx.z * 128 * HW;
    __hip_bfloat16* outb = tl + ooff + (size_t)blockIdx.z * (size_t)HW * 128;
#pragma unroll
    for (int j = 0; j < 32; j += 8)
        s[ty + j][tx] = inb[(size_t)(c0 + ty + j) * HW + hw0 + tx];
    __syncthreads();
#pragma unroll
    for (int j = 0; j < 32; j += 8)
        outb[(size_t)(hw0 + ty + j) * 128 + c0 + tx] = __float2bfloat16(s[tx][ty + j]);
}

// ---------------------------------------------------------------------------
// ROI align on channels-last bf16 fmaps. One block per ROI.
// ---------------------------------------------------------------------------
__global__ __launch_bounds__(256) void k_roi_cl(
    const __hip_bfloat16* __restrict__ tl, const float* __restrict__ rois,
    float* __restrict__ out)
{
    __shared__ int   s_a[NBINS][4];
    __shared__ float s_w[NBINS][4];
    __shared__ float s_o[NCH * NBINS];   // [c][bin]
    const int n   = blockIdx.x;
    const int tid = threadIdx.x;

    const float ry1 = rois[n*5+0], rx1 = rois[n*5+1];
    const float ry2 = rois[n*5+2], rx2 = rois[n*5+3];
    const int   b   = (int)rois[n*5+4];
    const float h = ry2 - ry1, w = rx2 - rx1;
    const float lraw = rintf(4.0f + log2f(sqrtf(h*w + 1e-12f)));
    int lvl = (int)lraw; lvl = lvl < 0 ? 0 : (lvl > 3 ? 3 : lvl);
    const int H = 256 >> lvl;
    const size_t lbase = (lvl==0) ? L0OFF : (lvl==1) ? L1OFF : (lvl==2) ? L2OFF : L3OFF;
    const __hip_bfloat16* bp = tl + lbase + (size_t)b * (size_t)(H*H) * NCH;

    const float Hf  = (float)H;
    const float y1p = ry1*Hf, x1p = rx1*Hf, y2p = ry2*Hf, x2p = rx2*Hf;
    const float bh = (y2p - y1p) / 7.0f, bw = (x2p - x1p) / 7.0f;

    if (tid < NBINS) {
        const int py = tid / 7, px = tid % 7;
        float sy = y1p + bh*((float)py + 0.5f);
        float sx = x1p + bw*((float)px + 0.5f);
        sy = fminf(fmaxf(sy, 0.0f), Hf - 1.0f);
        sx = fminf(fmaxf(sx, 0.0f), Hf - 1.0f);
        const float y0f = floorf(sy), x0f = floorf(sx);
        const int y0 = (int)y0f, x0 = (int)x0f;
        const int y1i = min(y0+1, H-1), x1i = min(x0+1, H-1);
        const float wy = sy - y0f, wx = sx - x0f;
        s_a[tid][0] = y0 *H + x0;
        s_a[tid][1] = y0 *H + x1i;
        s_a[tid][2] = y1i*H + x0;
        s_a[tid][3] = y1i*H + x1i;
        const float omy = 1.0f - wy, omx = 1.0f - wx;
        s_w[tid][0] = omy*omx; s_w[tid][1] = omy*wx;
        s_w[tid][2] = wy *omx; s_w[tid][3] = wy *wx;
    }
    __syncthreads();

    const int c2 = tid & 63;          // channel pair 0..63
    const int b0 = tid >> 6;          // 0..3
    for (int bin = b0; bin < NBINS; bin += 4) {
        float ax = 0.0f, ay = 0.0f;
#pragma unroll
        for (int tap = 0; tap < 4; ++tap) {
            const unsigned int u =
                *(const unsigned int*)(bp + (size_t)s_a[bin][tap] * NCH + 2*c2);
            const float lo = __uint_as_float(u << 16);
            const float hi = __uint_as_float(u & 0xffff0000u);
            const float wgt = s_w[bin][tap];
            ax += lo * wgt; ay += hi * wgt;
        }
        s_o[(2*c2)   * NBINS + bin] = ax;
        s_o[(2*c2+1) * NBINS + bin] = ay;
    }
    __syncthreads();

    float4* outn = (float4*)(out + (size_t)n * (NCH*NBINS));
    const float4* so4 = (const float4*)s_o;
    for (int t4 = tid; t4 < (NCH*NBINS)/4; t4 += 256)
        outn[t4] = so4[t4];
}

// ---------------------------------------------------------------------------
// Fallback ROI align (NCHW direct), used if ws too small for transpose.
// ---------------------------------------------------------------------------
__global__ __launch_bounds__(256) void k_roi(
    const float* __restrict__ f0, const float* __restrict__ f1,
    const float* __restrict__ f2, const float* __restrict__ f3,
    const float* __restrict__ rois, float* __restrict__ out)
{
    __shared__ int   s_a[NBINS][4];
    __shared__ float s_w[NBINS][4];
    const int n   = blockIdx.x;
    const int tid = threadIdx.x;

    const float ry1 = rois[n*5+0], rx1 = rois[n*5+1];
    const float ry2 = rois[n*5+2], rx2 = rois[n*5+3];
    const int   b   = (int)rois[n*5+4];
    const float h = ry2 - ry1, w = rx2 - rx1;
    const float lraw = rintf(4.0f + log2f(sqrtf(h*w + 1e-12f)));
    int lvl = (int)lraw; lvl = lvl < 0 ? 0 : (lvl > 3 ? 3 : lvl);
    const int H = 256 >> lvl;
    const float* f = (lvl==0) ? f0 : (lvl==1) ? f1 : (lvl==2) ? f2 : f3;

    const float Hf  = (float)H;
    const float y1p = ry1*Hf, x1p = rx1*Hf, y2p = ry2*Hf, x2p = rx2*Hf;
    const float bh = (y2p - y1p) / 7.0f, bw = (x2p - x1p) / 7.0f;

    if (tid < NBINS) {
        const int py = tid / 7, px = tid % 7;
        float sy = y1p + bh*((float)py + 0.5f);
        float sx = x1p + bw*((float)px + 0.5f);
        sy = fminf(fmaxf(sy, 0.0f), Hf - 1.0f);
        sx = fminf(fmaxf(sx, 0.0f), Hf - 1.0f);
        const float y0f = floorf(sy), x0f = floorf(sx);
        const int y0 = (int)y0f, x0 = (int)x0f;
        const int y1i = min(y0+1, H-1), x1i = min(x0+1, H-1);
        const float wy = sy - y0f, wx = sx - x0f;
        s_a[tid][0] = y0 *H + x0;
        s_a[tid][1] = y0 *H + x1i;
        s_a[tid][2] = y1i*H + x0;
        s_a[tid][3] = y1i*H + x1i;
        const float omy = 1.0f - wy, omx = 1.0f - wx;
        s_w[tid][0] = omy*omx; s_w[tid][1] = omy*wx;
        s_w[tid][2] = wy *omx; s_w[tid][3] = wy *wx;
    }
    __syncthreads();

    const int hw = H*H;
    const float* basep = f + (size_t)b * NCH * hw;
    float* outn = out + (size_t)n * (NCH*NBINS);
    for (int t = tid; t < NCH*NBINS; t += 256) {
        const int c   = t / NBINS;
        const int bin = t - c*NBINS;
        const float* p = basep + (size_t)c * hw;
        outn[t] = p[s_a[bin][0]]*s_w[bin][0] + p[s_a[bin][1]]*s_w[bin][1]
                + p[s_a[bin][2]]*s_w[bin][2] + p[s_a[bin][3]]*s_w[bin][3];
    }
}

// ---------------------------------------------------------------------------
// threefry2x32 (device) — exact JAX semantics
// ---------------------------------------------------------------------------
__device__ __forceinline__ uint32_t rotl32d(uint32_t v, int r) { return (v << r) | (v >> (32-r)); }

__device__ void tf2x32(uint32_t k0, uint32_t k1, uint32_t& x0, uint32_t& x1)
{
    const uint32_t ks2 = k0 ^ k1 ^ 0x1BD11BDAu;
    const int R0[4] = {13,15,26,6};
    const int R1[4] = {17,29,16,24};
    x0 += k0; x1 += k1;
#pragma unroll
    for (int r = 0; r < 4; ++r) { x0 += x1; x1 = rotl32d(x1, R0[r]); x1 ^= x0; }
    x0 += k1;  x1 += ks2 + 1u;
#pragma unroll
    for (int r = 0; r < 4; ++r) { x0 += x1; x1 = rotl32d(x1, R1[r]); x1 ^= x0; }
    x0 += ks2; x1 += k0 + 2u;
#pragma unroll
    for (int r = 0; r < 4; ++r) { x0 += x1; x1 = rotl32d(x1, R0[r]); x1 ^= x0; }
    x0 += k0;  x1 += k1 + 3u;
#pragma unroll
    for (int r = 0; r < 4; ++r) { x0 += x1; x1 = rotl32d(x1, R1[r]); x1 ^= x0; }
    x0 += k1;  x1 += ks2 + 4u;
#pragma unroll
    for (int r = 0; r < 4; ++r) { x0 += x1; x1 = rotl32d(x1, R0[r]); x1 ^= x0; }
    x0 += ks2; x1 += k0 + 5u;
}

__device__ __forceinline__ unsigned int monobits(float x) {
    unsigned int u = __float_as_uint(x);
    return (u & 0x80000000u) ? ~u : (u | 0x80000000u);
}

// ---------------------------------------------------------------------------
// k_prep: blocks 0..39  : perm key-gen -> T1/T2 + LDS histogram of top-12 bits
//         blocks 40..103: OHEM 13-bit histogram (LDS-aggregated)
//         block  104    : pos loss; block 105: bbox loss
// (hist arrays pre-zeroed by hipMemsetAsync)
// ---------------------------------------------------------------------------
__global__ __launch_bounds__(256) void k_prep(
    unsigned long long* __restrict__ T1, unsigned long long* __restrict__ T2,
    unsigned int* __restrict__ histA,
    unsigned int* __restrict__ histP1, unsigned int* __restrict__ histP2,
    const int* __restrict__ am, const float* __restrict__ logits,
    const float* __restrict__ pd, const float* __restrict__ td,
    float* __restrict__ prt)
{
    __shared__ unsigned int buf[ABINS];   // 32 KiB
    const int bid = blockIdx.x;
    const int t   = threadIdx.x;

    if (bid < 40) {
        // perm keys: i in [0,10000) -> elements (i, 10000+i) of both rounds
        unsigned int* lh1 = buf;            // 4096
        unsigned int* lh2 = buf + PBINS;    // 4096
        for (int b = t; b < 2*PBINS; b += 256) buf[b] = 0u;
        __syncthreads();
        const int i = bid*256 + t;
        if (i < POOLN/2) {
            uint32_t a0 = 0u, a1 = 2u; tf2x32(0u, 1u, a0, a1);
            uint32_t b0 = 1u, b1 = 3u; tf2x32(0u, 1u, b0, b1);
            uint32_t c0 = 0u, c1 = 2u; tf2x32(a0, b0, c0, c1);
            uint32_t d0 = 1u, d1 = 3u; tf2x32(a0, b0, d0, d1);
            uint32_t x0 = (uint32_t)i, x1 = (uint32_t)(POOLN/2 + i);
            tf2x32(a1, b1, x0, x1);
            T1[i]           = ((unsigned long long)x0 << 32) | (unsigned)i;
            T1[POOLN/2 + i] = ((unsigned long long)x1 << 32) | (unsigned)(POOLN/2 + i);
            atomicAdd(&lh1[x0 >> 20], 1u);
            atomicAdd(&lh1[x1 >> 20], 1u);
            uint32_t y0 = (uint32_t)i, y1 = (uint32_t)(POOLN/2 + i);
            tf2x32(c1, d1, y0, y1);
            T2[i]           = ((unsigned long long)y0 << 32) | (unsigned)i;
            T2[POOLN/2 + i] = ((unsigned long long)y1 << 32) | (unsigned)(POOLN/2 + i);
            atomicAdd(&lh2[y0 >> 20], 1u);
            atomicAdd(&lh2[y1 >> 20], 1u);
        }
        __syncthreads();
        for (int b = t; b < PBINS; b += 256) {
            unsigned int v = lh1[b]; if (v) atomicAdd(&histP1[b], v);
            v = lh2[b];              if (v) atomicAdd(&histP2[b], v);
        }
        return;
    }
    if (bid < 104) {
        for (int b = t; b < ABINS; b += 256) buf[b] = 0u;
        __syncthreads();
        for (int i = (bid-40)*256 + t; i < N_NEGA; i += 64*256) {
            const float l0 = logits[(size_t)(N_POSA+i)*2+0];
            const float l1 = logits[(size_t)(N_POSA+i)*2+1];
            atomicAdd(&buf[monobits(l0 - l1) >> (32-HBITS_A)], 1u);
        }
        __syncthreads();
        for (int b = t; b < ABINS; b += 256) {
            const unsigned int v = buf[b];
            if (v) atomicAdd(&histA[b], v);
        }
        return;
    }
    __shared__ float red[256];
    float s = 0.0f;
    if (bid == 104) {
        for (int i = t; i < N_POSA; i += 256) {
            const int tgt = am[i];
            const float l0 = logits[(size_t)i*2+0], l1 = logits[(size_t)i*2+1];
            const float m = fmaxf(l0, l1);
            const float lse = logf(expf(l0-m) + expf(l1-m));
            const float lt = (tgt == 0) ? l0 : l1;
            s += (lt - m) - lse;
        }
    } else {
        for (int i = t; i < N_POSA*4; i += 256) {
            const float d = fabsf(pd[i] - td[i]);
            s += (d < 1.0f) ? 0.5f*d*d : d - 0.5f;
        }
    }
    red[t] = s;
    __syncthreads();
    for (int off = 128; off > 0; off >>= 1) {
        if (t < off) red[t] += red[t+off];
        __syncthreads();
    }
    if (t == 0) prt[bid - 104] = red[0];
}

// ---------------------------------------------------------------------------
// k_scan: one block. Exclusive scans of histA (8192), histP1, histP2 (4096).
// Writes base + mutable-base copies, and the OHEM threshold bin sel[0].
// ---------------------------------------------------------------------------
__device__ void scan_one(const unsigned int* __restrict__ hist,
                         unsigned int* __restrict__ base,
                         unsigned int* __restrict__ basem,
                         int n, unsigned int* lds)
{
    const int t = threadIdx.x;        // 1024 threads
    const int chunk = n >> 10;
    unsigned int s = 0;
    for (int k = 0; k < chunk; ++k) s += hist[t*chunk + k];
    lds[t] = s;
    __syncthreads();
    for (int off = 1; off < 1024; off <<= 1) {
        unsigned int v = (t >= off) ? lds[t-off] : 0u;
        __syncthreads();
        lds[t] += v;
        __syncthreads();
    }
    unsigned int run = (t == 0) ? 0u : lds[t-1];
    for (int k = 0; k < chunk; ++k) {
        base[t*chunk+k] = run; basem[t*chunk+k] = run;
        run += hist[t*chunk+k];
    }
    if (t == 1023) { base[n] = run; basem[n] = run; }
    __syncthreads();
}

__global__ __launch_bounds__(1024) void k_scan(
    const unsigned int* __restrict__ histA,
    const unsigned int* __restrict__ histP1, const unsigned int* __restrict__ histP2,
    unsigned int* __restrict__ baseA,  unsigned int* __restrict__ baseAm,
    unsigned int* __restrict__ baseP1, unsigned int* __restrict__ baseP1m,
    unsigned int* __restrict__ baseP2, unsigned int* __restrict__ baseP2m,
    unsigned int* __restrict__ sel)
{
    __shared__ unsigned int lds[1024];
    scan_one(histA, baseA, baseAm, ABINS, lds);
    scan_one(histP1, baseP1, baseP1m, PBINS, lds);
    scan_one(histP2, baseP2, baseP2m, PBINS, lds);
    const int t = threadIdx.x;
    const int chunk = ABINS >> 10;
    for (int k = 0; k < chunk; ++k) {
        const int bin = t*chunk + k;
        if (baseA[bin] < POOLN && baseA[bin] + histA[bin] >= POOLN)
            sel[0] = (unsigned int)bin;
    }
}

// ---------------------------------------------------------------------------
// k_scatter: pool elements into A grouped by bin; perm keys into P1/P2
// grouped by bin (within-bin order arbitrary; fixed by per-bin sort).
// ---------------------------------------------------------------------------
__global__ __launch_bounds__(256) void k_scatter(
    const float* __restrict__ logits,
    const unsigned long long* __restrict__ T1, const unsigned long long* __restrict__ T2,
    unsigned long long* __restrict__ A,
    unsigned long long* __restrict__ P1, unsigned long long* __restrict__ P2,
    unsigned int* __restrict__ baseAm, unsigned int* __restrict__ baseP1m,
    unsigned int* __restrict__ baseP2m, const unsigned int* __restrict__ sel)
{
    const int i = blockIdx.x*256 + threadIdx.x;
    if (i < N_NEGA) {
        const float l0 = logits[(size_t)(N_POSA+i)*2+0];
        const float l1 = logits[(size_t)(N_POSA+i)*2+1];
        const unsigned int bits = monobits(l0 - l1);
        const unsigned int bin = bits >> (32-HBITS_A);
        if (bin <= sel[0]) {
            const unsigned int pos = atomicAdd(&baseAm[bin], 1u);
            A[pos] = ((unsigned long long)bits << 32) | (unsigned)i;
        }
    }
    if (i < POOLN) {
        const unsigned long long k1 = T1[i];
        const unsigned int p1 = atomicAdd(&baseP1m[(unsigned)(k1 >> 52)], 1u);
        P1[p1] = k1;
        const unsigned long long k2 = T2[i];
        const unsigned int p2 = atomicAdd(&baseP2m[(unsigned)(k2 >> 52)], 1u);
        P2[p2] = k2;
    }
}

// ---------------------------------------------------------------------------
// k_binsort: blocks [0,8192): per-A-bin LDS bitonic (bins <= sel[0]).
//            blocks [8192,8200): thread-per-P-bin insertion sort (in L2).
// ---------------------------------------------------------------------------
__global__ __launch_bounds__(1024) void k_binsort(
    unsigned long long* __restrict__ A,
    unsigned long long* __restrict__ P1, unsigned long long* __restrict__ P2,
    const unsigned int* __restrict__ baseA,
    const unsigned int* __restrict__ baseP1, const unsigned int* __restrict__ baseP2,
    const unsigned int* __restrict__ sel)
{
    __shared__ unsigned long long s[ACAP];   // 64 KiB
    const int bid = blockIdx.x;
    const int t   = threadIdx.x;
    if (bid < ABINS) {
        if ((unsigned)bid > sel[0]) return;
        const int base = (int)baseA[bid];
        const int cnt  = (int)baseA[bid+1] - base;
        if (cnt < 2) return;
        int m = 2; while (m < cnt) m <<= 1;   // <= ACAP by construction margin
        for (int k = t; k < m; k += 1024) s[k] = (k < cnt) ? A[base+k] : ~0ull;
        __syncthreads();
        for (int ksz = 2; ksz <= m; ksz <<= 1) {
            for (int j = ksz>>1; j >= 1; j >>= 1) {
                for (int p = t; p < (m>>1); p += 1024) {
                    const int i = ((p & ~(j-1)) << 1) | (p & (j-1));
                    const int l = i | j;
                    const bool up = ((i & ksz) == 0);
                    unsigned long long a = s[i], b = s[l];
                    if ((a > b) == up) { s[i] = b; s[l] = a; }
                }
                __syncthreads();
            }
        }
        for (int k = t; k < cnt; k += 1024) A[base+k] = s[k];
        return;
    }
    const int g = (bid - ABINS)*1024 + t;     // 0..8191
    unsigned long long* P = (g < PBINS) ? P1 : P2;
    const unsigned int* bp = (g < PBINS) ? baseP1 : baseP2;
    const int bin = g & (PBINS-1);
    const int b0  = (int)bp[bin];
    const int cnt = (int)bp[bin+1] - b0;
    for (int k = 1; k < cnt; ++k) {
        const unsigned long long key = P[b0+k];
        int j = k-1;
        while (j >= 0 && P[b0+j] > key) { P[b0+j+1] = P[b0+j]; --j; }
        P[b0+j+1] = key;
    }
}

// ---------------------------------------------------------------------------
__global__ __launch_bounds__(256) void k_final(
    const float* __restrict__ logits, const unsigned long long* __restrict__ A,
    const unsigned long long* __restrict__ P1, const unsigned long long* __restrict__ P2,
    const float* __restrict__ partial, float* __restrict__ out2)
{
    __shared__ float red[256];
    const int t = threadIdx.x;
    float s = 0.0f;
    for (int j = t; j < N_POSA; j += 256) {
        const int i2 = (int)(unsigned)(P2[j] & 0xffffffffu);
        const int r  = (int)(unsigned)(P1[i2] & 0xffffffffu);
        const unsigned int i = (unsigned)(A[r] & 0xffffffffu);
        const float l0 = logits[(size_t)(N_POSA+i)*2+0];
        const float l1 = logits[(size_t)(N_POSA+i)*2+1];
        const float m = fmaxf(l0, l1);
        s += (l0 - m) - logf(expf(l0-m) + expf(l1-m));
    }
    red[t] = s;
    __syncthreads();
    for (int off = 128; off > 0; off >>= 1) {
        if (t < off) red[t] += red[t+off];
        __syncthreads();
    }
    if (t == 0) {
        const float neg_loss = -red[0] / (float)N_POSA;
        const float pos_loss = -partial[0] / (float)N_POSA;
        out2[0] = 0.5f * (pos_loss + neg_loss);
        out2[1] = partial[1] / (float)(N_POSA*4);
    }
}

// ---------------------------------------------------------------------------
extern "C" void kernel_launch(void* const* d_in, const int* in_sizes, int n_in,
                              void* d_out, int out_size, void* d_ws, size_t ws_size,
                              hipStream_t stream)
{
    const float* f0     = (const float*)d_in[0];
    const float* f1     = (const float*)d_in[1];
    const float* f2     = (const float*)d_in[2];
    const float* f3     = (const float*)d_in[3];
    const float* rois   = (const float*)d_in[4];
    const int*   am     = (const int*)  d_in[5];
    const float* logits = (const float*)d_in[6];
    const float* pd     = (const float*)d_in[7];
    const float* td     = (const float*)d_in[8];
    float* out = (float*)d_out;

    char* ws = (char*)d_ws;
    unsigned long long* A      = (unsigned long long*)(ws);            // 262144
    unsigned long long* T1     = (unsigned long long*)(ws +  262144); // 160000
    unsigned long long* T2     = (unsigned long long*)(ws +  422144); // 160000
    unsigned long long* P1     = (unsigned long long*)(ws +  582144); // 160000
    unsigned long long* P2     = (unsigned long long*)(ws +  742144); // 160000
    unsigned int*       histA  = (unsigned int*)      (ws +  902144); // 32768
    unsigned int*       histP1 = (unsigned int*)      (ws +  934912); // 16384
    unsigned int*       histP2 = (unsigned int*)      (ws +  951296); // 16384
    unsigned int*       baseA  = (unsigned int*)      (ws +  967680); // 32832
    unsigned int*       baseAm = (unsigned int*)      (ws + 1000512); // 32832
    unsigned int*       baseP1 = (unsigned int*)      (ws + 1033344); // 16448
    unsigned int*       baseP1m= (unsigned int*)      (ws + 1049792); // 16448
    unsigned int*       baseP2 = (unsigned int*)      (ws + 1066240); // 16448
    unsigned int*       baseP2m= (unsigned int*)      (ws + 1082688); // 16448
    unsigned int*       sel    = (unsigned int*)      (ws + 1099136); // 64
    float*              prt    = (float*)             (ws + 1099200); // 64
    __hip_bfloat16*     tl     = (__hip_bfloat16*)    (ws + 1099264); // 44564480
    const size_t NEED = 1099264ull + TLELEMS * 2ull;

    // zero all three histograms (contiguous 64 KiB)
    hipMemsetAsync(histA, 0, 65536, stream);

    // losses + perm key-gen + histograms
    k_prep<<<106, 256, 0, stream>>>(T1, T2, histA, histP1, histP2,
                                    am, logits, pd, td, prt);

    // ROI align
    if (ws_size >= NEED) {
        k_tr<<<dim3(2720, 4, 2), dim3(32,8), 0, stream>>>(f0, f1, f2, f3, tl);
        k_roi_cl<<<NROIS, 256, 0, stream>>>(tl, rois, out);
    } else {
        k_roi<<<NROIS, 256, 0, stream>>>(f0, f1, f2, f3, rois, out);
    }

    // scans + threshold, scatter, per-bin sorts
    k_scan<<<1, 1024, 0, stream>>>(histA, histP1, histP2,
                                   baseA, baseAm, baseP1, baseP1m,
                                   baseP2, baseP2m, sel);
    k_scatter<<<(N_NEGA+255)/256, 256, 0, stream>>>(logits, T1, T2, A, P1, P2,
                                                    baseAm, baseP1m, baseP2m, sel);
    k_binsort<<<ABINS + 8, 1024, 0, stream>>>(A, P1, P2, baseA, baseP1, baseP2, sel);

    // final scalars
    k_final<<<1, 256, 0, stream>>>(logits, A, P1, P2, prt,
                                   out + (size_t)NROIS*NCH*NBINS);
}

// Round 5
// 145.122 us; speedup vs baseline: 13.6733x; 1.4008x over previous
//
#include <hip/hip_runtime.h>
#include <hip/hip_bf16.h>
#include <cstdint>

#define NROIS  4000
#define NCH    128
#define NBINS  49
#define N_POSA 1000
#define N_NEGA 200000
#define POOLN  20000
#define HBITS_A 13
#define ABINS  8192
#define PBINS  4096
#define ACAP   8192

// tl (channels-last bf16 fmaps) element offsets per level
#define L0OFF 0ull
#define L1OFF 16777216ull
#define L2OFF 20971520ull
#define L3OFF 22020096ull
#define TLELEMS 22282240ull

// ---------------------------------------------------------------------------
// Fused NCHW -> NHWC transpose (f32 -> bf16), all 4 levels in one grid.
// ---------------------------------------------------------------------------
__global__ __launch_bounds__(256) void k_tr(
    const float* __restrict__ f0, const float* __restrict__ f1,
    const float* __restrict__ f2, const float* __restrict__ f3,
    __hip_bfloat16* __restrict__ tl)
{
    __shared__ float s[32][33];
    const int bx = blockIdx.x;
    int lvl, start;
    if      (bx < 2048) { lvl = 0; start = 0;    }
    else if (bx < 2560) { lvl = 1; start = 2048; }
    else if (bx < 2688) { lvl = 2; start = 2560; }
    else                { lvl = 3; start = 2688; }
    const int HW = 65536 >> (2*lvl);
    const float* in = (lvl==0) ? f0 : (lvl==1) ? f1 : (lvl==2) ? f2 : f3;
    const size_t ooff = (lvl==0) ? L0OFF : (lvl==1) ? L1OFF : (lvl==2) ? L2OFF : L3OFF;

    const int tx = threadIdx.x, ty = threadIdx.y;
    const int hw0 = (bx - start) * 32, c0 = blockIdx.y * 32;
    const float* inb = in + (size_t)blockIdx.z * 128 * HW;
    __hip_bfloat16* outb = tl + ooff + (size_t)blockIdx.z * (size_t)HW * 128;
#pragma unroll
    for (int j = 0; j < 32; j += 8)
        s[ty + j][tx] = inb[(size_t)(c0 + ty + j) * HW + hw0 + tx];
    __syncthreads();
#pragma unroll
    for (int j = 0; j < 32; j += 8)
        outb[(size_t)(hw0 + ty + j) * 128 + c0 + tx] = __float2bfloat16(s[tx][ty + j]);
}

// ---------------------------------------------------------------------------
// ROI align on channels-last bf16 fmaps. One block per ROI.
// ---------------------------------------------------------------------------
__global__ __launch_bounds__(256) void k_roi_cl(
    const __hip_bfloat16* __restrict__ tl, const float* __restrict__ rois,
    float* __restrict__ out)
{
    __shared__ int   s_a[NBINS][4];
    __shared__ float s_w[NBINS][4];
    __shared__ float s_o[NCH * NBINS];   // [c][bin]
    const int n   = blockIdx.x;
    const int tid = threadIdx.x;

    const float ry1 = rois[n*5+0], rx1 = rois[n*5+1];
    const float ry2 = rois[n*5+2], rx2 = rois[n*5+3];
    const int   b   = (int)rois[n*5+4];
    const float h = ry2 - ry1, w = rx2 - rx1;
    const float lraw = rintf(4.0f + log2f(sqrtf(h*w + 1e-12f)));
    int lvl = (int)lraw; lvl = lvl < 0 ? 0 : (lvl > 3 ? 3 : lvl);
    const int H = 256 >> lvl;
    const size_t lbase = (lvl==0) ? L0OFF : (lvl==1) ? L1OFF : (lvl==2) ? L2OFF : L3OFF;
    const __hip_bfloat16* bp = tl + lbase + (size_t)b * (size_t)(H*H) * NCH;

    const float Hf  = (float)H;
    const float y1p = ry1*Hf, x1p = rx1*Hf, y2p = ry2*Hf, x2p = rx2*Hf;
    const float bh = (y2p - y1p) / 7.0f, bw = (x2p - x1p) / 7.0f;

    if (tid < NBINS) {
        const int py = tid / 7, px = tid % 7;
        float sy = y1p + bh*((float)py + 0.5f);
        float sx = x1p + bw*((float)px + 0.5f);
        sy = fminf(fmaxf(sy, 0.0f), Hf - 1.0f);
        sx = fminf(fmaxf(sx, 0.0f), Hf - 1.0f);
        const float y0f = floorf(sy), x0f = floorf(sx);
        const int y0 = (int)y0f, x0 = (int)x0f;
        const int y1i = min(y0+1, H-1), x1i = min(x0+1, H-1);
        const float wy = sy - y0f, wx = sx - x0f;
        s_a[tid][0] = y0 *H + x0;
        s_a[tid][1] = y0 *H + x1i;
        s_a[tid][2] = y1i*H + x0;
        s_a[tid][3] = y1i*H + x1i;
        const float omy = 1.0f - wy, omx = 1.0f - wx;
        s_w[tid][0] = omy*omx; s_w[tid][1] = omy*wx;
        s_w[tid][2] = wy *omx; s_w[tid][3] = wy *wx;
    }
    __syncthreads();

    const int c2 = tid & 63;          // channel pair 0..63
    const int b0 = tid >> 6;          // 0..3
    for (int bin = b0; bin < NBINS; bin += 4) {
        float ax = 0.0f, ay = 0.0f;
#pragma unroll
        for (int tap = 0; tap < 4; ++tap) {
            const unsigned int u =
                *(const unsigned int*)(bp + (size_t)s_a[bin][tap] * NCH + 2*c2);
            const float lo = __uint_as_float(u << 16);
            const float hi = __uint_as_float(u & 0xffff0000u);
            const float wgt = s_w[bin][tap];
            ax += lo * wgt; ay += hi * wgt;
        }
        s_o[(2*c2)   * NBINS + bin] = ax;
        s_o[(2*c2+1) * NBINS + bin] = ay;
    }
    __syncthreads();

    float4* outn = (float4*)(out + (size_t)n * (NCH*NBINS));
    const float4* so4 = (const float4*)s_o;
    for (int t4 = tid; t4 < (NCH*NBINS)/4; t4 += 256)
        outn[t4] = so4[t4];
}

// ---------------------------------------------------------------------------
// Fallback ROI align (NCHW direct), used if ws too small for transpose.
// ---------------------------------------------------------------------------
__global__ __launch_bounds__(256) void k_roi(
    const float* __restrict__ f0, const float* __restrict__ f1,
    const float* __restrict__ f2, const float* __restrict__ f3,
    const float* __restrict__ rois, float* __restrict__ out)
{
    __shared__ int   s_a[NBINS][4];
    __shared__ float s_w[NBINS][4];
    const int n   = blockIdx.x;
    const int tid = threadIdx.x;

    const float ry1 = rois[n*5+0], rx1 = rois[n*5+1];
    const float ry2 = rois[n*5+2], rx2 = rois[n*5+3];
    const int   b   = (int)rois[n*5+4];
    const float h = ry2 - ry1, w = rx2 - rx1;
    const float lraw = rintf(4.0f + log2f(sqrtf(h*w + 1e-12f)));
    int lvl = (int)lraw; lvl = lvl < 0 ? 0 : (lvl > 3 ? 3 : lvl);
    const int H = 256 >> lvl;
    const float* f = (lvl==0) ? f0 : (lvl==1) ? f1 : (lvl==2) ? f2 : f3;

    const float Hf  = (float)H;
    const float y1p = ry1*Hf, x1p = rx1*Hf, y2p = ry2*Hf, x2p = rx2*Hf;
    const float bh = (y2p - y1p) / 7.0f, bw = (x2p - x1p) / 7.0f;

    if (tid < NBINS) {
        const int py = tid / 7, px = tid % 7;
        float sy = y1p + bh*((float)py + 0.5f);
        float sx = x1p + bw*((float)px + 0.5f);
        sy = fminf(fmaxf(sy, 0.0f), Hf - 1.0f);
        sx = fminf(fmaxf(sx, 0.0f), Hf - 1.0f);
        const float y0f = floorf(sy), x0f = floorf(sx);
        const int y0 = (int)y0f, x0 = (int)x0f;
        const int y1i = min(y0+1, H-1), x1i = min(x0+1, H-1);
        const float wy = sy - y0f, wx = sx - x0f;
        s_a[tid][0] = y0 *H + x0;
        s_a[tid][1] = y0 *H + x1i;
        s_a[tid][2] = y1i*H + x0;
        s_a[tid][3] = y1i*H + x1i;
        const float omy = 1.0f - wy, omx = 1.0f - wx;
        s_w[tid][0] = omy*omx; s_w[tid][1] = omy*wx;
        s_w[tid][2] = wy *omx; s_w[tid][3] = wy *wx;
    }
    __syncthreads();

    const int hw = H*H;
    const float* basep = f + (size_t)b * NCH * hw;
    float* outn = out + (size_t)n * (NCH*NBINS);
    for (int t = tid; t < NCH*NBINS; t += 256) {
        const int c   = t / NBINS;
        const int bin = t - c*NBINS;
        const float* p = basep + (size_t)c * hw;
        outn[t] = p[s_a[bin][0]]*s_w[bin][0] + p[s_a[bin][1]]*s_w[bin][1]
                + p[s_a[bin][2]]*s_w[bin][2] + p[s_a[bin][3]]*s_w[bin][3];
    }
}

// ---------------------------------------------------------------------------
// threefry2x32 (device) — exact JAX semantics
// ---------------------------------------------------------------------------
__device__ __forceinline__ uint32_t rotl32d(uint32_t v, int r) { return (v << r) | (v >> (32-r)); }

__device__ void tf2x32(uint32_t k0, uint32_t k1, uint32_t& x0, uint32_t& x1)
{
    const uint32_t ks2 = k0 ^ k1 ^ 0x1BD11BDAu;
    const int R0[4] = {13,15,26,6};
    const int R1[4] = {17,29,16,24};
    x0 += k0; x1 += k1;
#pragma unroll
    for (int r = 0; r < 4; ++r) { x0 += x1; x1 = rotl32d(x1, R0[r]); x1 ^= x0; }
    x0 += k1;  x1 += ks2 + 1u;
#pragma unroll
    for (int r = 0; r < 4; ++r) { x0 += x1; x1 = rotl32d(x1, R1[r]); x1 ^= x0; }
    x0 += ks2; x1 += k0 + 2u;
#pragma unroll
    for (int r = 0; r < 4; ++r) { x0 += x1; x1 = rotl32d(x1, R0[r]); x1 ^= x0; }
    x0 += k0;  x1 += k1 + 3u;
#pragma unroll
    for (int r = 0; r < 4; ++r) { x0 += x1; x1 = rotl32d(x1, R1[r]); x1 ^= x0; }
    x0 += k1;  x1 += ks2 + 4u;
#pragma unroll
    for (int r = 0; r < 4; ++r) { x0 += x1; x1 = rotl32d(x1, R0[r]); x1 ^= x0; }
    x0 += ks2; x1 += k0 + 5u;
}

__device__ __forceinline__ unsigned int monobits(float x) {
    unsigned int u = __float_as_uint(x);
    return (u & 0x80000000u) ? ~u : (u | 0x80000000u);
}

// ---------------------------------------------------------------------------
// k_prep: blocks 0..39  : perm key-gen -> T1/T2 + LDS histogram of top-12 bits
//         blocks 40..103: OHEM 13-bit histogram (LDS-aggregated)
//         block  104    : pos loss; block 105: bbox loss
// (hist arrays pre-zeroed by hipMemsetAsync)
// ---------------------------------------------------------------------------
__global__ __launch_bounds__(256) void k_prep(
    unsigned long long* __restrict__ T1, unsigned long long* __restrict__ T2,
    unsigned int* __restrict__ histA,
    unsigned int* __restrict__ histP1, unsigned int* __restrict__ histP2,
    const int* __restrict__ am, const float* __restrict__ logits,
    const float* __restrict__ pd, const float* __restrict__ td,
    float* __restrict__ prt)
{
    __shared__ unsigned int buf[ABINS];   // 32 KiB
    const int bid = blockIdx.x;
    const int t   = threadIdx.x;

    if (bid < 40) {
        unsigned int* lh1 = buf;            // 4096
        unsigned int* lh2 = buf + PBINS;    // 4096
        for (int b = t; b < 2*PBINS; b += 256) buf[b] = 0u;
        __syncthreads();
        const int i = bid*256 + t;
        if (i < POOLN/2) {
            uint32_t a0 = 0u, a1 = 2u; tf2x32(0u, 1u, a0, a1);
            uint32_t b0 = 1u, b1 = 3u; tf2x32(0u, 1u, b0, b1);
            uint32_t c0 = 0u, c1 = 2u; tf2x32(a0, b0, c0, c1);
            uint32_t d0 = 1u, d1 = 3u; tf2x32(a0, b0, d0, d1);
            uint32_t x0 = (uint32_t)i, x1 = (uint32_t)(POOLN/2 + i);
            tf2x32(a1, b1, x0, x1);
            T1[i]           = ((unsigned long long)x0 << 32) | (unsigned)i;
            T1[POOLN/2 + i] = ((unsigned long long)x1 << 32) | (unsigned)(POOLN/2 + i);
            atomicAdd(&lh1[x0 >> 20], 1u);
            atomicAdd(&lh1[x1 >> 20], 1u);
            uint32_t y0 = (uint32_t)i, y1 = (uint32_t)(POOLN/2 + i);
            tf2x32(c1, d1, y0, y1);
            T2[i]           = ((unsigned long long)y0 << 32) | (unsigned)i;
            T2[POOLN/2 + i] = ((unsigned long long)y1 << 32) | (unsigned)(POOLN/2 + i);
            atomicAdd(&lh2[y0 >> 20], 1u);
            atomicAdd(&lh2[y1 >> 20], 1u);
        }
        __syncthreads();
        for (int b = t; b < PBINS; b += 256) {
            unsigned int v = lh1[b]; if (v) atomicAdd(&histP1[b], v);
            v = lh2[b];              if (v) atomicAdd(&histP2[b], v);
        }
        return;
    }
    if (bid < 104) {
        for (int b = t; b < ABINS; b += 256) buf[b] = 0u;
        __syncthreads();
        for (int i = (bid-40)*256 + t; i < N_NEGA; i += 64*256) {
            const float l0 = logits[(size_t)(N_POSA+i)*2+0];
            const float l1 = logits[(size_t)(N_POSA+i)*2+1];
            atomicAdd(&buf[monobits(l0 - l1) >> (32-HBITS_A)], 1u);
        }
        __syncthreads();
        for (int b = t; b < ABINS; b += 256) {
            const unsigned int v = buf[b];
            if (v) atomicAdd(&histA[b], v);
        }
        return;
    }
    __shared__ float red[256];
    float s = 0.0f;
    if (bid == 104) {
        for (int i = t; i < N_POSA; i += 256) {
            const int tgt = am[i];
            const float l0 = logits[(size_t)i*2+0], l1 = logits[(size_t)i*2+1];
            const float m = fmaxf(l0, l1);
            const float lse = logf(expf(l0-m) + expf(l1-m));
            const float lt = (tgt == 0) ? l0 : l1;
            s += (lt - m) - lse;
        }
    } else {
        for (int i = t; i < N_POSA*4; i += 256) {
            const float d = fabsf(pd[i] - td[i]);
            s += (d < 1.0f) ? 0.5f*d*d : d - 0.5f;
        }
    }
    red[t] = s;
    __syncthreads();
    for (int off = 128; off > 0; off >>= 1) {
        if (t < off) red[t] += red[t+off];
        __syncthreads();
    }
    if (t == 0) prt[bid - 104] = red[0];
}

// ---------------------------------------------------------------------------
// k_scan: one block. Exclusive scans of histA (8192), histP1, histP2 (4096).
// ---------------------------------------------------------------------------
__device__ void scan_one(const unsigned int* __restrict__ hist,
                         unsigned int* __restrict__ base,
                         unsigned int* __restrict__ basem,
                         int n, unsigned int* lds)
{
    const int t = threadIdx.x;        // 1024 threads
    const int chunk = n >> 10;
    unsigned int s = 0;
    for (int k = 0; k < chunk; ++k) s += hist[t*chunk + k];
    lds[t] = s;
    __syncthreads();
    for (int off = 1; off < 1024; off <<= 1) {
        unsigned int v = (t >= off) ? lds[t-off] : 0u;
        __syncthreads();
        lds[t] += v;
        __syncthreads();
    }
    unsigned int run = (t == 0) ? 0u : lds[t-1];
    for (int k = 0; k < chunk; ++k) {
        base[t*chunk+k] = run; basem[t*chunk+k] = run;
        run += hist[t*chunk+k];
    }
    if (t == 1023) { base[n] = run; basem[n] = run; }
    __syncthreads();
}

__global__ __launch_bounds__(1024) void k_scan(
    const unsigned int* __restrict__ histA,
    const unsigned int* __restrict__ histP1, const unsigned int* __restrict__ histP2,
    unsigned int* __restrict__ baseA,  unsigned int* __restrict__ baseAm,
    unsigned int* __restrict__ baseP1, unsigned int* __restrict__ baseP1m,
    unsigned int* __restrict__ baseP2, unsigned int* __restrict__ baseP2m,
    unsigned int* __restrict__ sel)
{
    __shared__ unsigned int lds[1024];
    scan_one(histA, baseA, baseAm, ABINS, lds);
    scan_one(histP1, baseP1, baseP1m, PBINS, lds);
    scan_one(histP2, baseP2, baseP2m, PBINS, lds);
    const int t = threadIdx.x;
    const int chunk = ABINS >> 10;
    for (int k = 0; k < chunk; ++k) {
        const int bin = t*chunk + k;
        if (baseA[bin] < POOLN && baseA[bin] + histA[bin] >= POOLN)
            sel[0] = (unsigned int)bin;
    }
}

// ---------------------------------------------------------------------------
// k_scatter: blocks 0..63  : A-scatter, block-privatized two-pass (LDS counts,
//                            one global atomic per populated bin per block).
//            blocks 64..142: P1/P2 direct scatter (short chains, <=~15/bin).
// ---------------------------------------------------------------------------
__global__ __launch_bounds__(256) void k_scatter(
    const float* __restrict__ logits,
    const unsigned long long* __restrict__ T1, const unsigned long long* __restrict__ T2,
    unsigned long long* __restrict__ A,
    unsigned long long* __restrict__ P1, unsigned long long* __restrict__ P2,
    unsigned int* __restrict__ baseAm, unsigned int* __restrict__ baseP1m,
    unsigned int* __restrict__ baseP2m, const unsigned int* __restrict__ sel)
{
    __shared__ unsigned int lh[ABINS];   // 32 KiB
    const int bid = blockIdx.x;
    const int t   = threadIdx.x;
    if (bid < 64) {
        for (int b = t; b < ABINS; b += 256) lh[b] = 0u;
        __syncthreads();
        const unsigned int selv = sel[0];
        const int start = bid * (N_NEGA/64);          // 3125 each, exact
        const int end   = start + (N_NEGA/64);
        for (int i = start + t; i < end; i += 256) {
            const float l0 = logits[(size_t)(N_POSA+i)*2+0];
            const float l1 = logits[(size_t)(N_POSA+i)*2+1];
            const unsigned int bin = monobits(l0 - l1) >> (32-HBITS_A);
            if (bin <= selv) atomicAdd(&lh[bin], 1u);
        }
        __syncthreads();
        for (int b = t; b < ABINS; b += 256) {
            const unsigned int cnt = lh[b];
            if (cnt) lh[b] = atomicAdd(&baseAm[b], cnt);
        }
        __syncthreads();
        for (int i = start + t; i < end; i += 256) {
            const float l0 = logits[(size_t)(N_POSA+i)*2+0];
            const float l1 = logits[(size_t)(N_POSA+i)*2+1];
            const unsigned int bits = monobits(l0 - l1);
            const unsigned int bin = bits >> (32-HBITS_A);
            if (bin <= selv) {
                const unsigned int pos = atomicAdd(&lh[bin], 1u);
                A[pos] = ((unsigned long long)bits << 32) | (unsigned)i;
            }
        }
        return;
    }
    const int i = (bid - 64)*256 + t;
    if (i < POOLN) {
        const unsigned long long k1 = T1[i];
        const unsigned int p1 = atomicAdd(&baseP1m[(unsigned)(k1 >> 52)], 1u);
        P1[p1] = k1;
        const unsigned long long k2 = T2[i];
        const unsigned int p2 = atomicAdd(&baseP2m[(unsigned)(k2 >> 52)], 1u);
        P2[p2] = k2;
    }
}

// ---------------------------------------------------------------------------
// k_binsort: blocks [0,8192): per-A-bin LDS bitonic (bins <= sel[0]).
//            blocks [8192,8200): thread-per-P-bin insertion sort (in L2).
// ---------------------------------------------------------------------------
__global__ __launch_bounds__(1024) void k_binsort(
    unsigned long long* __restrict__ A,
    unsigned long long* __restrict__ P1, unsigned long long* __restrict__ P2,
    const unsigned int* __restrict__ baseA,
    const unsigned int* __restrict__ baseP1, const unsigned int* __restrict__ baseP2,
    const unsigned int* __restrict__ sel)
{
    __shared__ unsigned long long s[ACAP];   // 64 KiB
    const int bid = blockIdx.x;
    const int t   = threadIdx.x;
    if (bid < ABINS) {
        if ((unsigned)bid > sel[0]) return;
        const int base = (int)baseA[bid];
        const int cnt  = (int)baseA[bid+1] - base;
        if (cnt < 2) return;
        int m = 2; while (m < cnt) m <<= 1;
        for (int k = t; k < m; k += 1024) s[k] = (k < cnt) ? A[base+k] : ~0ull;
        __syncthreads();
        for (int ksz = 2; ksz <= m; ksz <<= 1) {
            for (int j = ksz>>1; j >= 1; j >>= 1) {
                for (int p = t; p < (m>>1); p += 1024) {
                    const int i = ((p & ~(j-1)) << 1) | (p & (j-1));
                    const int l = i | j;
                    const bool up = ((i & ksz) == 0);
                    unsigned long long a = s[i], b = s[l];
                    if ((a > b) == up) { s[i] = b; s[l] = a; }
                }
                __syncthreads();
            }
        }
        for (int k = t; k < cnt; k += 1024) A[base+k] = s[k];
        return;
    }
    const int g = (bid - ABINS)*1024 + t;     // 0..8191
    unsigned long long* P = (g < PBINS) ? P1 : P2;
    const unsigned int* bp = (g < PBINS) ? baseP1 : baseP2;
    const int bin = g & (PBINS-1);
    const int b0  = (int)bp[bin];
    const int cnt = (int)bp[bin+1] - b0;
    for (int k = 1; k < cnt; ++k) {
        const unsigned long long key = P[b0+k];
        int j = k-1;
        while (j >= 0 && P[b0+j] > key) { P[b0+j+1] = P[b0+j]; --j; }
        P[b0+j+1] = key;
    }
}

// ---------------------------------------------------------------------------
__global__ __launch_bounds__(256) void k_final(
    const float* __restrict__ logits, const unsigned long long* __restrict__ A,
    const unsigned long long* __restrict__ P1, const unsigned long long* __restrict__ P2,
    const float* __restrict__ partial, float* __restrict__ out2)
{
    __shared__ float red[256];
    const int t = threadIdx.x;
    float s = 0.0f;
    for (int j = t; j < N_POSA; j += 256) {
        const int i2 = (int)(unsigned)(P2[j] & 0xffffffffu);
        const int r  = (int)(unsigned)(P1[i2] & 0xffffffffu);
        const unsigned int i = (unsigned)(A[r] & 0xffffffffu);
        const float l0 = logits[(size_t)(N_POSA+i)*2+0];
        const float l1 = logits[(size_t)(N_POSA+i)*2+1];
        const float m = fmaxf(l0, l1);
        s += (l0 - m) - logf(expf(l0-m) + expf(l1-m));
    }
    red[t] = s;
    __syncthreads();
    for (int off = 128; off > 0; off >>= 1) {
        if (t < off) red[t] += red[t+off];
        __syncthreads();
    }
    if (t == 0) {
        const float neg_loss = -red[0] / (float)N_POSA;
        const float pos_loss = -partial[0] / (float)N_POSA;
        out2[0] = 0.5f * (pos_loss + neg_loss);
        out2[1] = partial[1] / (float)(N_POSA*4);
    }
}

// ---------------------------------------------------------------------------
extern "C" void kernel_launch(void* const* d_in, const int* in_sizes, int n_in,
                              void* d_out, int out_size, void* d_ws, size_t ws_size,
                              hipStream_t stream)
{
    const float* f0     = (const float*)d_in[0];
    const float* f1     = (const float*)d_in[1];
    const float* f2     = (const float*)d_in[2];
    const float* f3     = (const float*)d_in[3];
    const float* rois   = (const float*)d_in[4];
    const int*   am     = (const int*)  d_in[5];
    const float* logits = (const float*)d_in[6];
    const float* pd     = (const float*)d_in[7];
    const float* td     = (const float*)d_in[8];
    float* out = (float*)d_out;

    char* ws = (char*)d_ws;
    unsigned long long* A      = (unsigned long long*)(ws);            // 262144
    unsigned long long* T1     = (unsigned long long*)(ws +  262144); // 160000
    unsigned long long* T2     = (unsigned long long*)(ws +  422144); // 160000
    unsigned long long* P1     = (unsigned long long*)(ws +  582144); // 160000
    unsigned long long* P2     = (unsigned long long*)(ws +  742144); // 160000
    unsigned int*       histA  = (unsigned int*)      (ws +  902144); // 32768
    unsigned int*       histP1 = (unsigned int*)      (ws +  934912); // 16384
    unsigned int*       histP2 = (unsigned int*)      (ws +  951296); // 16384
    unsigned int*       baseA  = (unsigned int*)      (ws +  967680); // 32832
    unsigned int*       baseAm = (unsigned int*)      (ws + 1000512); // 32832
    unsigned int*       baseP1 = (unsigned int*)      (ws + 1033344); // 16448
    unsigned int*       baseP1m= (unsigned int*)      (ws + 1049792); // 16448
    unsigned int*       baseP2 = (unsigned int*)      (ws + 1066240); // 16448
    unsigned int*       baseP2m= (unsigned int*)      (ws + 1082688); // 16448
    unsigned int*       sel    = (unsigned int*)      (ws + 1099136); // 64
    float*              prt    = (float*)             (ws + 1099200); // 64
    __hip_bfloat16*     tl     = (__hip_bfloat16*)    (ws + 1099264); // 44564480
    const size_t NEED = 1099264ull + TLELEMS * 2ull;

    // zero all three histograms (contiguous 64 KiB)
    hipMemsetAsync(histA, 0, 65536, stream);

    // losses + perm key-gen + histograms
    k_prep<<<106, 256, 0, stream>>>(T1, T2, histA, histP1, histP2,
                                    am, logits, pd, td, prt);

    // ROI align
    if (ws_size >= NEED) {
        k_tr<<<dim3(2720, 4, 2), dim3(32,8), 0, stream>>>(f0, f1, f2, f3, tl);
        k_roi_cl<<<NROIS, 256, 0, stream>>>(tl, rois, out);
    } else {
        k_roi<<<NROIS, 256, 0, stream>>>(f0, f1, f2, f3, rois, out);
    }

    // scans + threshold, scatter, per-bin sorts
    k_scan<<<1, 1024, 0, stream>>>(histA, histP1, histP2,
                                   baseA, baseAm, baseP1, baseP1m,
                                   baseP2, baseP2m, sel);
    k_scatter<<<64 + (POOLN+255)/256, 256, 0, stream>>>(logits, T1, T2, A, P1, P2,
                                                        baseAm, baseP1m, baseP2m, sel);
    k_binsort<<<ABINS + 8, 1024, 0, stream>>>(A, P1, P2, baseA, baseP1, baseP2, sel);

    // final scalars
    k_final<<<1, 256, 0, stream>>>(logits, A, P1, P2, prt,
                                   out + (size_t)NROIS*NCH*NBINS);
}

// Round 6
// 144.615 us; speedup vs baseline: 13.7212x; 1.0035x over previous
//
#include <hip/hip_runtime.h>
#include <hip/hip_bf16.h>
#include <cstdint>

#define NROIS  4000
#define NCH    128
#define NBINS  49
#define N_POSA 1000
#define N_NEGA 200000
#define POOLN  20000
#define HBITS_A 13
#define ABINS  8192
#define PBINS  4096
#define ACAP   8192

// tl (channels-last bf16 fmaps) element offsets per level
#define L0OFF 0ull
#define L1OFF 16777216ull
#define L2OFF 20971520ull
#define L3OFF 22020096ull
#define TLELEMS 22282240ull

// ---------------------------------------------------------------------------
// k_zero: zero the three contiguous histograms (16384 uints = 64 KiB).
// Replaces a hipMemsetAsync graph node that ran as a 60 us fillBuffer.
// ---------------------------------------------------------------------------
__global__ void k_zero(unsigned int* __restrict__ h)
{
    h[blockIdx.x*256 + threadIdx.x] = 0u;
}

// ---------------------------------------------------------------------------
// Fused NCHW -> NHWC transpose (f32 -> bf16), all 4 levels in one grid.
// ---------------------------------------------------------------------------
__global__ __launch_bounds__(256) void k_tr(
    const float* __restrict__ f0, const float* __restrict__ f1,
    const float* __restrict__ f2, const float* __restrict__ f3,
    __hip_bfloat16* __restrict__ tl)
{
    __shared__ float s[32][33];
    const int bx = blockIdx.x;
    int lvl, start;
    if      (bx < 2048) { lvl = 0; start = 0;    }
    else if (bx < 2560) { lvl = 1; start = 2048; }
    else if (bx < 2688) { lvl = 2; start = 2560; }
    else                { lvl = 3; start = 2688; }
    const int HW = 65536 >> (2*lvl);
    const float* in = (lvl==0) ? f0 : (lvl==1) ? f1 : (lvl==2) ? f2 : f3;
    const size_t ooff = (lvl==0) ? L0OFF : (lvl==1) ? L1OFF : (lvl==2) ? L2OFF : L3OFF;

    const int tx = threadIdx.x, ty = threadIdx.y;
    const int hw0 = (bx - start) * 32, c0 = blockIdx.y * 32;
    const float* inb = in + (size_t)blockIdx.z * 128 * HW;
    __hip_bfloat16* outb = tl + ooff + (size_t)blockIdx.z * (size_t)HW * 128;
#pragma unroll
    for (int j = 0; j < 32; j += 8)
        s[ty + j][tx] = inb[(size_t)(c0 + ty + j) * HW + hw0 + tx];
    __syncthreads();
#pragma unroll
    for (int j = 0; j < 32; j += 8)
        outb[(size_t)(hw0 + ty + j) * 128 + c0 + tx] = __float2bfloat16(s[tx][ty + j]);
}

// ---------------------------------------------------------------------------
// ROI align on channels-last bf16 fmaps. One block per ROI.
// ---------------------------------------------------------------------------
__global__ __launch_bounds__(256) void k_roi_cl(
    const __hip_bfloat16* __restrict__ tl, const float* __restrict__ rois,
    float* __restrict__ out)
{
    __shared__ int   s_a[NBINS][4];
    __shared__ float s_w[NBINS][4];
    __shared__ float s_o[NCH * NBINS];   // [c][bin]
    const int n   = blockIdx.x;
    const int tid = threadIdx.x;

    const float ry1 = rois[n*5+0], rx1 = rois[n*5+1];
    const float ry2 = rois[n*5+2], rx2 = rois[n*5+3];
    const int   b   = (int)rois[n*5+4];
    const float h = ry2 - ry1, w = rx2 - rx1;
    const float lraw = rintf(4.0f + log2f(sqrtf(h*w + 1e-12f)));
    int lvl = (int)lraw; lvl = lvl < 0 ? 0 : (lvl > 3 ? 3 : lvl);
    const int H = 256 >> lvl;
    const size_t lbase = (lvl==0) ? L0OFF : (lvl==1) ? L1OFF : (lvl==2) ? L2OFF : L3OFF;
    const __hip_bfloat16* bp = tl + lbase + (size_t)b * (size_t)(H*H) * NCH;

    const float Hf  = (float)H;
    const float y1p = ry1*Hf, x1p = rx1*Hf, y2p = ry2*Hf, x2p = rx2*Hf;
    const float bh = (y2p - y1p) / 7.0f, bw = (x2p - x1p) / 7.0f;

    if (tid < NBINS) {
        const int py = tid / 7, px = tid % 7;
        float sy = y1p + bh*((float)py + 0.5f);
        float sx = x1p + bw*((float)px + 0.5f);
        sy = fminf(fmaxf(sy, 0.0f), Hf - 1.0f);
        sx = fminf(fmaxf(sx, 0.0f), Hf - 1.0f);
        const float y0f = floorf(sy), x0f = floorf(sx);
        const int y0 = (int)y0f, x0 = (int)x0f;
        const int y1i = min(y0+1, H-1), x1i = min(x0+1, H-1);
        const float wy = sy - y0f, wx = sx - x0f;
        s_a[tid][0] = y0 *H + x0;
        s_a[tid][1] = y0 *H + x1i;
        s_a[tid][2] = y1i*H + x0;
        s_a[tid][3] = y1i*H + x1i;
        const float omy = 1.0f - wy, omx = 1.0f - wx;
        s_w[tid][0] = omy*omx; s_w[tid][1] = omy*wx;
        s_w[tid][2] = wy *omx; s_w[tid][3] = wy *wx;
    }
    __syncthreads();

    const int c2 = tid & 63;          // channel pair 0..63
    const int b0 = tid >> 6;          // 0..3
    for (int bin = b0; bin < NBINS; bin += 4) {
        float ax = 0.0f, ay = 0.0f;
#pragma unroll
        for (int tap = 0; tap < 4; ++tap) {
            const unsigned int u =
                *(const unsigned int*)(bp + (size_t)s_a[bin][tap] * NCH + 2*c2);
            const float lo = __uint_as_float(u << 16);
            const float hi = __uint_as_float(u & 0xffff0000u);
            const float wgt = s_w[bin][tap];
            ax += lo * wgt; ay += hi * wgt;
        }
        s_o[(2*c2)   * NBINS + bin] = ax;
        s_o[(2*c2+1) * NBINS + bin] = ay;
    }
    __syncthreads();

    float4* outn = (float4*)(out + (size_t)n * (NCH*NBINS));
    const float4* so4 = (const float4*)s_o;
    for (int t4 = tid; t4 < (NCH*NBINS)/4; t4 += 256)
        outn[t4] = so4[t4];
}

// ---------------------------------------------------------------------------
// Fallback ROI align (NCHW direct), used if ws too small for transpose.
// ---------------------------------------------------------------------------
__global__ __launch_bounds__(256) void k_roi(
    const float* __restrict__ f0, const float* __restrict__ f1,
    const float* __restrict__ f2, const float* __restrict__ f3,
    const float* __restrict__ rois, float* __restrict__ out)
{
    __shared__ int   s_a[NBINS][4];
    __shared__ float s_w[NBINS][4];
    const int n   = blockIdx.x;
    const int tid = threadIdx.x;

    const float ry1 = rois[n*5+0], rx1 = rois[n*5+1];
    const float ry2 = rois[n*5+2], rx2 = rois[n*5+3];
    const int   b   = (int)rois[n*5+4];
    const float h = ry2 - ry1, w = rx2 - rx1;
    const float lraw = rintf(4.0f + log2f(sqrtf(h*w + 1e-12f)));
    int lvl = (int)lraw; lvl = lvl < 0 ? 0 : (lvl > 3 ? 3 : lvl);
    const int H = 256 >> lvl;
    const float* f = (lvl==0) ? f0 : (lvl==1) ? f1 : (lvl==2) ? f2 : f3;

    const float Hf  = (float)H;
    const float y1p = ry1*Hf, x1p = rx1*Hf, y2p = ry2*Hf, x2p = rx2*Hf;
    const float bh = (y2p - y1p) / 7.0f, bw = (x2p - x1p) / 7.0f;

    if (tid < NBINS) {
        const int py = tid / 7, px = tid % 7;
        float sy = y1p + bh*((float)py + 0.5f);
        float sx = x1p + bw*((float)px + 0.5f);
        sy = fminf(fmaxf(sy, 0.0f), Hf - 1.0f);
        sx = fminf(fmaxf(sx, 0.0f), Hf - 1.0f);
        const float y0f = floorf(sy), x0f = floorf(sx);
        const int y0 = (int)y0f, x0 = (int)x0f;
        const int y1i = min(y0+1, H-1), x1i = min(x0+1, H-1);
        const float wy = sy - y0f, wx = sx - x0f;
        s_a[tid][0] = y0 *H + x0;
        s_a[tid][1] = y0 *H + x1i;
        s_a[tid][2] = y1i*H + x0;
        s_a[tid][3] = y1i*H + x1i;
        const float omy = 1.0f - wy, omx = 1.0f - wx;
        s_w[tid][0] = omy*omx; s_w[tid][1] = omy*wx;
        s_w[tid][2] = wy *omx; s_w[tid][3] = wy *wx;
    }
    __syncthreads();

    const int hw = H*H;
    const float* basep = f + (size_t)b * NCH * hw;
    float* outn = out + (size_t)n * (NCH*NBINS);
    for (int t = tid; t < NCH*NBINS; t += 256) {
        const int c   = t / NBINS;
        const int bin = t - c*NBINS;
        const float* p = basep + (size_t)c * hw;
        outn[t] = p[s_a[bin][0]]*s_w[bin][0] + p[s_a[bin][1]]*s_w[bin][1]
                + p[s_a[bin][2]]*s_w[bin][2] + p[s_a[bin][3]]*s_w[bin][3];
    }
}

// ---------------------------------------------------------------------------
// threefry2x32 (device) — exact JAX semantics
// ---------------------------------------------------------------------------
__device__ __forceinline__ uint32_t rotl32d(uint32_t v, int r) { return (v << r) | (v >> (32-r)); }

__device__ void tf2x32(uint32_t k0, uint32_t k1, uint32_t& x0, uint32_t& x1)
{
    const uint32_t ks2 = k0 ^ k1 ^ 0x1BD11BDAu;
    const int R0[4] = {13,15,26,6};
    const int R1[4] = {17,29,16,24};
    x0 += k0; x1 += k1;
#pragma unroll
    for (int r = 0; r < 4; ++r) { x0 += x1; x1 = rotl32d(x1, R0[r]); x1 ^= x0; }
    x0 += k1;  x1 += ks2 + 1u;
#pragma unroll
    for (int r = 0; r < 4; ++r) { x0 += x1; x1 = rotl32d(x1, R1[r]); x1 ^= x0; }
    x0 += ks2; x1 += k0 + 2u;
#pragma unroll
    for (int r = 0; r < 4; ++r) { x0 += x1; x1 = rotl32d(x1, R0[r]); x1 ^= x0; }
    x0 += k0;  x1 += k1 + 3u;
#pragma unroll
    for (int r = 0; r < 4; ++r) { x0 += x1; x1 = rotl32d(x1, R1[r]); x1 ^= x0; }
    x0 += k1;  x1 += ks2 + 4u;
#pragma unroll
    for (int r = 0; r < 4; ++r) { x0 += x1; x1 = rotl32d(x1, R0[r]); x1 ^= x0; }
    x0 += ks2; x1 += k0 + 5u;
}

__device__ __forceinline__ unsigned int monobits(float x) {
    unsigned int u = __float_as_uint(x);
    return (u & 0x80000000u) ? ~u : (u | 0x80000000u);
}

// ---------------------------------------------------------------------------
// k_prep: blocks 0..39  : perm key-gen -> T1/T2 + LDS histogram of top-12 bits
//         blocks 40..103: OHEM 13-bit histogram (LDS-aggregated)
//         block  104    : pos loss; block 105: bbox loss
// (hist arrays zeroed by k_zero)
// ---------------------------------------------------------------------------
__global__ __launch_bounds__(256) void k_prep(
    unsigned long long* __restrict__ T1, unsigned long long* __restrict__ T2,
    unsigned int* __restrict__ histA,
    unsigned int* __restrict__ histP1, unsigned int* __restrict__ histP2,
    const int* __restrict__ am, const float* __restrict__ logits,
    const float* __restrict__ pd, const float* __restrict__ td,
    float* __restrict__ prt)
{
    __shared__ unsigned int buf[ABINS];   // 32 KiB
    const int bid = blockIdx.x;
    const int t   = threadIdx.x;

    if (bid < 40) {
        unsigned int* lh1 = buf;            // 4096
        unsigned int* lh2 = buf + PBINS;    // 4096
        for (int b = t; b < 2*PBINS; b += 256) buf[b] = 0u;
        __syncthreads();
        const int i = bid*256 + t;
        if (i < POOLN/2) {
            uint32_t a0 = 0u, a1 = 2u; tf2x32(0u, 1u, a0, a1);
            uint32_t b0 = 1u, b1 = 3u; tf2x32(0u, 1u, b0, b1);
            uint32_t c0 = 0u, c1 = 2u; tf2x32(a0, b0, c0, c1);
            uint32_t d0 = 1u, d1 = 3u; tf2x32(a0, b0, d0, d1);
            uint32_t x0 = (uint32_t)i, x1 = (uint32_t)(POOLN/2 + i);
            tf2x32(a1, b1, x0, x1);
            T1[i]           = ((unsigned long long)x0 << 32) | (unsigned)i;
            T1[POOLN/2 + i] = ((unsigned long long)x1 << 32) | (unsigned)(POOLN/2 + i);
            atomicAdd(&lh1[x0 >> 20], 1u);
            atomicAdd(&lh1[x1 >> 20], 1u);
            uint32_t y0 = (uint32_t)i, y1 = (uint32_t)(POOLN/2 + i);
            tf2x32(c1, d1, y0, y1);
            T2[i]           = ((unsigned long long)y0 << 32) | (unsigned)i;
            T2[POOLN/2 + i] = ((unsigned long long)y1 << 32) | (unsigned)(POOLN/2 + i);
            atomicAdd(&lh2[y0 >> 20], 1u);
            atomicAdd(&lh2[y1 >> 20], 1u);
        }
        __syncthreads();
        for (int b = t; b < PBINS; b += 256) {
            unsigned int v = lh1[b]; if (v) atomicAdd(&histP1[b], v);
            v = lh2[b];              if (v) atomicAdd(&histP2[b], v);
        }
        return;
    }
    if (bid < 104) {
        for (int b = t; b < ABINS; b += 256) buf[b] = 0u;
        __syncthreads();
        for (int i = (bid-40)*256 + t; i < N_NEGA; i += 64*256) {
            const float l0 = logits[(size_t)(N_POSA+i)*2+0];
            const float l1 = logits[(size_t)(N_POSA+i)*2+1];
            atomicAdd(&buf[monobits(l0 - l1) >> (32-HBITS_A)], 1u);
        }
        __syncthreads();
        for (int b = t; b < ABINS; b += 256) {
            const unsigned int v = buf[b];
            if (v) atomicAdd(&histA[b], v);
        }
        return;
    }
    __shared__ float red[256];
    float s = 0.0f;
    if (bid == 104) {
        for (int i = t; i < N_POSA; i += 256) {
            const int tgt = am[i];
            const float l0 = logits[(size_t)i*2+0], l1 = logits[(size_t)i*2+1];
            const float m = fmaxf(l0, l1);
            const float lse = logf(expf(l0-m) + expf(l1-m));
            const float lt = (tgt == 0) ? l0 : l1;
            s += (lt - m) - lse;
        }
    } else {
        for (int i = t; i < N_POSA*4; i += 256) {
            const float d = fabsf(pd[i] - td[i]);
            s += (d < 1.0f) ? 0.5f*d*d : d - 0.5f;
        }
    }
    red[t] = s;
    __syncthreads();
    for (int off = 128; off > 0; off >>= 1) {
        if (t < off) red[t] += red[t+off];
        __syncthreads();
    }
    if (t == 0) prt[bid - 104] = red[0];
}

// ---------------------------------------------------------------------------
// k_scan: one block. Exclusive scans of histA (8192), histP1, histP2 (4096).
// ---------------------------------------------------------------------------
__device__ void scan_one(const unsigned int* __restrict__ hist,
                         unsigned int* __restrict__ base,
                         unsigned int* __restrict__ basem,
                         int n, unsigned int* lds)
{
    const int t = threadIdx.x;        // 1024 threads
    const int chunk = n >> 10;
    unsigned int s = 0;
    for (int k = 0; k < chunk; ++k) s += hist[t*chunk + k];
    lds[t] = s;
    __syncthreads();
    for (int off = 1; off < 1024; off <<= 1) {
        unsigned int v = (t >= off) ? lds[t-off] : 0u;
        __syncthreads();
        lds[t] += v;
        __syncthreads();
    }
    unsigned int run = (t == 0) ? 0u : lds[t-1];
    for (int k = 0; k < chunk; ++k) {
        base[t*chunk+k] = run; basem[t*chunk+k] = run;
        run += hist[t*chunk+k];
    }
    if (t == 1023) { base[n] = run; basem[n] = run; }
    __syncthreads();
}

__global__ __launch_bounds__(1024) void k_scan(
    const unsigned int* __restrict__ histA,
    const unsigned int* __restrict__ histP1, const unsigned int* __restrict__ histP2,
    unsigned int* __restrict__ baseA,  unsigned int* __restrict__ baseAm,
    unsigned int* __restrict__ baseP1, unsigned int* __restrict__ baseP1m,
    unsigned int* __restrict__ baseP2, unsigned int* __restrict__ baseP2m,
    unsigned int* __restrict__ sel)
{
    __shared__ unsigned int lds[1024];
    scan_one(histA, baseA, baseAm, ABINS, lds);
    scan_one(histP1, baseP1, baseP1m, PBINS, lds);
    scan_one(histP2, baseP2, baseP2m, PBINS, lds);
    const int t = threadIdx.x;
    const int chunk = ABINS >> 10;
    for (int k = 0; k < chunk; ++k) {
        const int bin = t*chunk + k;
        if (baseA[bin] < POOLN && baseA[bin] + histA[bin] >= POOLN)
            sel[0] = (unsigned int)bin;
    }
}

// ---------------------------------------------------------------------------
// k_scatter: blocks 0..63  : A-scatter, block-privatized two-pass (LDS counts,
//                            one global atomic per populated bin per block).
//            blocks 64..142: P1/P2 direct scatter (short chains, <=~15/bin).
// ---------------------------------------------------------------------------
__global__ __launch_bounds__(256) void k_scatter(
    const float* __restrict__ logits,
    const unsigned long long* __restrict__ T1, const unsigned long long* __restrict__ T2,
    unsigned long long* __restrict__ A,
    unsigned long long* __restrict__ P1, unsigned long long* __restrict__ P2,
    unsigned int* __restrict__ baseAm, unsigned int* __restrict__ baseP1m,
    unsigned int* __restrict__ baseP2m, const unsigned int* __restrict__ sel)
{
    __shared__ unsigned int lh[ABINS];   // 32 KiB
    const int bid = blockIdx.x;
    const int t   = threadIdx.x;
    if (bid < 64) {
        for (int b = t; b < ABINS; b += 256) lh[b] = 0u;
        __syncthreads();
        const unsigned int selv = sel[0];
        const int start = bid * (N_NEGA/64);          // 3125 each, exact
        const int end   = start + (N_NEGA/64);
        for (int i = start + t; i < end; i += 256) {
            const float l0 = logits[(size_t)(N_POSA+i)*2+0];
            const float l1 = logits[(size_t)(N_POSA+i)*2+1];
            const unsigned int bin = monobits(l0 - l1) >> (32-HBITS_A);
            if (bin <= selv) atomicAdd(&lh[bin], 1u);
        }
        __syncthreads();
        for (int b = t; b < ABINS; b += 256) {
            const unsigned int cnt = lh[b];
            if (cnt) lh[b] = atomicAdd(&baseAm[b], cnt);
        }
        __syncthreads();
        for (int i = start + t; i < end; i += 256) {
            const float l0 = logits[(size_t)(N_POSA+i)*2+0];
            const float l1 = logits[(size_t)(N_POSA+i)*2+1];
            const unsigned int bits = monobits(l0 - l1);
            const unsigned int bin = bits >> (32-HBITS_A);
            if (bin <= selv) {
                const unsigned int pos = atomicAdd(&lh[bin], 1u);
                A[pos] = ((unsigned long long)bits << 32) | (unsigned)i;
            }
        }
        return;
    }
    const int i = (bid - 64)*256 + t;
    if (i < POOLN) {
        const unsigned long long k1 = T1[i];
        const unsigned int p1 = atomicAdd(&baseP1m[(unsigned)(k1 >> 52)], 1u);
        P1[p1] = k1;
        const unsigned long long k2 = T2[i];
        const unsigned int p2 = atomicAdd(&baseP2m[(unsigned)(k2 >> 52)], 1u);
        P2[p2] = k2;
    }
}

// ---------------------------------------------------------------------------
// k_binsort: blocks [0,8192): per-A-bin LDS bitonic (bins <= sel[0]).
//            blocks [8192,8200): thread-per-P-bin insertion sort (in L2).
// ---------------------------------------------------------------------------
__global__ __launch_bounds__(1024) void k_binsort(
    unsigned long long* __restrict__ A,
    unsigned long long* __restrict__ P1, unsigned long long* __restrict__ P2,
    const unsigned int* __restrict__ baseA,
    const unsigned int* __restrict__ baseP1, const unsigned int* __restrict__ baseP2,
    const unsigned int* __restrict__ sel)
{
    __shared__ unsigned long long s[ACAP];   // 64 KiB
    const int bid = blockIdx.x;
    const int t   = threadIdx.x;
    if (bid < ABINS) {
        if ((unsigned)bid > sel[0]) return;
        const int base = (int)baseA[bid];
        const int cnt  = (int)baseA[bid+1] - base;
        if (cnt < 2) return;
        int m = 2; while (m < cnt) m <<= 1;
        for (int k = t; k < m; k += 1024) s[k] = (k < cnt) ? A[base+k] : ~0ull;
        __syncthreads();
        for (int ksz = 2; ksz <= m; ksz <<= 1) {
            for (int j = ksz>>1; j >= 1; j >>= 1) {
                for (int p = t; p < (m>>1); p += 1024) {
                    const int i = ((p & ~(j-1)) << 1) | (p & (j-1));
                    const int l = i | j;
                    const bool up = ((i & ksz) == 0);
                    unsigned long long a = s[i], b = s[l];
                    if ((a > b) == up) { s[i] = b; s[l] = a; }
                }
                __syncthreads();
            }
        }
        for (int k = t; k < cnt; k += 1024) A[base+k] = s[k];
        return;
    }
    const int g = (bid - ABINS)*1024 + t;     // 0..8191
    unsigned long long* P = (g < PBINS) ? P1 : P2;
    const unsigned int* bp = (g < PBINS) ? baseP1 : baseP2;
    const int bin = g & (PBINS-1);
    const int b0  = (int)bp[bin];
    const int cnt = (int)bp[bin+1] - b0;
    for (int k = 1; k < cnt; ++k) {
        const unsigned long long key = P[b0+k];
        int j = k-1;
        while (j >= 0 && P[b0+j] > key) { P[b0+j+1] = P[b0+j]; --j; }
        P[b0+j+1] = key;
    }
}

// ---------------------------------------------------------------------------
__global__ __launch_bounds__(256) void k_final(
    const float* __restrict__ logits, const unsigned long long* __restrict__ A,
    const unsigned long long* __restrict__ P1, const unsigned long long* __restrict__ P2,
    const float* __restrict__ partial, float* __restrict__ out2)
{
    __shared__ float red[256];
    const int t = threadIdx.x;
    float s = 0.0f;
    for (int j = t; j < N_POSA; j += 256) {
        const int i2 = (int)(unsigned)(P2[j] & 0xffffffffu);
        const int r  = (int)(unsigned)(P1[i2] & 0xffffffffu);
        const unsigned int i = (unsigned)(A[r] & 0xffffffffu);
        const float l0 = logits[(size_t)(N_POSA+i)*2+0];
        const float l1 = logits[(size_t)(N_POSA+i)*2+1];
        const float m = fmaxf(l0, l1);
        s += (l0 - m) - logf(expf(l0-m) + expf(l1-m));
    }
    red[t] = s;
    __syncthreads();
    for (int off = 128; off > 0; off >>= 1) {
        if (t < off) red[t] += red[t+off];
        __syncthreads();
    }
    if (t == 0) {
        const float neg_loss = -red[0] / (float)N_POSA;
        const float pos_loss = -partial[0] / (float)N_POSA;
        out2[0] = 0.5f * (pos_loss + neg_loss);
        out2[1] = partial[1] / (float)(N_POSA*4);
    }
}

// ---------------------------------------------------------------------------
extern "C" void kernel_launch(void* const* d_in, const int* in_sizes, int n_in,
                              void* d_out, int out_size, void* d_ws, size_t ws_size,
                              hipStream_t stream)
{
    const float* f0     = (const float*)d_in[0];
    const float* f1     = (const float*)d_in[1];
    const float* f2     = (const float*)d_in[2];
    const float* f3     = (const float*)d_in[3];
    const float* rois   = (const float*)d_in[4];
    const int*   am     = (const int*)  d_in[5];
    const float* logits = (const float*)d_in[6];
    const float* pd     = (const float*)d_in[7];
    const float* td     = (const float*)d_in[8];
    float* out = (float*)d_out;

    char* ws = (char*)d_ws;
    unsigned long long* A      = (unsigned long long*)(ws);            // 262144
    unsigned long long* T1     = (unsigned long long*)(ws +  262144); // 160000
    unsigned long long* T2     = (unsigned long long*)(ws +  422144); // 160000
    unsigned long long* P1     = (unsigned long long*)(ws +  582144); // 160000
    unsigned long long* P2     = (unsigned long long*)(ws +  742144); // 160000
    unsigned int*       histA  = (unsigned int*)      (ws +  902144); // 32768
    unsigned int*       histP1 = (unsigned int*)      (ws +  934912); // 16384
    unsigned int*       histP2 = (unsigned int*)      (ws +  951296); // 16384
    unsigned int*       baseA  = (unsigned int*)      (ws +  967680); // 32832
    unsigned int*       baseAm = (unsigned int*)      (ws + 1000512); // 32832
    unsigned int*       baseP1 = (unsigned int*)      (ws + 1033344); // 16448
    unsigned int*       baseP1m= (unsigned int*)      (ws + 1049792); // 16448
    unsigned int*       baseP2 = (unsigned int*)      (ws + 1066240); // 16448
    unsigned int*       baseP2m= (unsigned int*)      (ws + 1082688); // 16448
    unsigned int*       sel    = (unsigned int*)      (ws + 1099136); // 64
    float*              prt    = (float*)             (ws + 1099200); // 64
    __hip_bfloat16*     tl     = (__hip_bfloat16*)    (ws + 1099264); // 44564480
    const size_t NEED = 1099264ull + TLELEMS * 2ull;

    // zero all three histograms (contiguous 64 KiB) — kernel, not memset node
    k_zero<<<64, 256, 0, stream>>>(histA);

    // losses + perm key-gen + histograms
    k_prep<<<106, 256, 0, stream>>>(T1, T2, histA, histP1, histP2,
                                    am, logits, pd, td, prt);

    // ROI align
    if (ws_size >= NEED) {
        k_tr<<<dim3(2720, 4, 2), dim3(32,8), 0, stream>>>(f0, f1, f2, f3, tl);
        k_roi_cl<<<NROIS, 256, 0, stream>>>(tl, rois, out);
    } else {
        k_roi<<<NROIS, 256, 0, stream>>>(f0, f1, f2, f3, rois, out);
    }

    // scans + threshold, scatter, per-bin sorts
    k_scan<<<1, 1024, 0, stream>>>(histA, histP1, histP2,
                                   baseA, baseAm, baseP1, baseP1m,
                                   baseP2, baseP2m, sel);
    k_scatter<<<64 + (POOLN+255)/256, 256, 0, stream>>>(logits, T1, T2, A, P1, P2,
                                                        baseAm, baseP1m, baseP2m, sel);
    k_binsort<<<ABINS + 8, 1024, 0, stream>>>(A, P1, P2, baseA, baseP1, baseP2, sel);

    // final scalars
    k_final<<<1, 256, 0, stream>>>(logits, A, P1, P2, prt,
                                   out + (size_t)NROIS*NCH*NBINS);
}